// Round 6
// baseline (1111.805 us; speedup 1.0000x reference)
//
#include <hip/hip_runtime.h>
#include <hip/hip_bf16.h>

typedef unsigned short ushort_t;
typedef short s8v __attribute__((ext_vector_type(8)));   // 8 bf16 bit-patterns
typedef float f32x4 __attribute__((ext_vector_type(4)));

// Problem constants
constexpr int B_ = 2;
constexpr int C_ = 256;
constexpr int S_TOT = 48 * 48;   // 2304
constexpr int HEADS_ = 8;
#define INV_SQRT_DH 0.17677669529663688f

// ---------------------------------------------------------------------------
// Kernel 1: MLP layer  out[b][s][co] = relu( sum_ci in[b][s][ci]*W[ci][co] + b )
// ---------------------------------------------------------------------------
template<int IN_MODE>
__global__ __launch_bounds__(256) void k_mlp(const float* __restrict__ in,
                                             const float* __restrict__ Wm,
                                             const float* __restrict__ bias,
                                             float* __restrict__ out) {
  __shared__ __align__(16) float in_s[32][260];
  const int tid = threadIdx.x;
  const int s0 = blockIdx.x * 32;
  const int b  = blockIdx.y;

  if (IN_MODE == 0) {
    for (int idx = tid; idx < 32 * 256; idx += 256) {
      int ci = idx >> 5, r = idx & 31;
      in_s[r][ci] = in[((size_t)b * C_ + ci) * S_TOT + s0 + r];
    }
  } else {
    for (int idx = tid; idx < 32 * 256; idx += 256) {
      int r = idx >> 8, ci = idx & 255;
      in_s[r][ci] = in[((size_t)b * S_TOT + s0 + r) * C_ + ci];
    }
  }
  __syncthreads();

  const int co = tid;
  float acc[32];
#pragma unroll
  for (int r = 0; r < 32; ++r) acc[r] = 0.f;

  for (int c4 = 0; c4 < 64; ++c4) {
    const float w0 = Wm[(c4 * 4 + 0) * C_ + co];
    const float w1 = Wm[(c4 * 4 + 1) * C_ + co];
    const float w2 = Wm[(c4 * 4 + 2) * C_ + co];
    const float w3 = Wm[(c4 * 4 + 3) * C_ + co];
#pragma unroll
    for (int r = 0; r < 32; ++r) {
      float4 a = *(const float4*)&in_s[r][c4 * 4];
      acc[r] = fmaf(a.x, w0, fmaf(a.y, w1, fmaf(a.z, w2, fmaf(a.w, w3, acc[r]))));
    }
  }

  const float bi = bias[co];
#pragma unroll 4
  for (int r = 0; r < 32; ++r) {
    out[((size_t)b * S_TOT + s0 + r) * C_ + co] = fmaxf(acc[r] + bi, 0.f);
  }
}

// ---------------------------------------------------------------------------
// Kernel 1b: split f32 -> (bf16 hi, bf16 lo) planes.
// ---------------------------------------------------------------------------
__device__ __forceinline__ ushort_t bf16_rn(float x) {
  unsigned u = __float_as_uint(x);
  return (ushort_t)((u + 0x7fffu + ((u >> 16) & 1u)) >> 16);
}

__global__ __launch_bounds__(256) void k_split(const float* __restrict__ in,
                                               ushort_t* __restrict__ hi,
                                               ushort_t* __restrict__ lo) {
  size_t idx = ((size_t)blockIdx.x * 256 + threadIdx.x) * 4;
  float4 v = *(const float4*)(in + idx);
  ushort_t h0 = bf16_rn(v.x), h1 = bf16_rn(v.y), h2 = bf16_rn(v.z), h3 = bf16_rn(v.w);
  float r0 = __uint_as_float((unsigned)h0 << 16);
  float r1 = __uint_as_float((unsigned)h1 << 16);
  float r2 = __uint_as_float((unsigned)h2 << 16);
  float r3 = __uint_as_float((unsigned)h3 << 16);
  ushort_t l0 = bf16_rn(v.x - r0), l1 = bf16_rn(v.y - r1);
  ushort_t l2 = bf16_rn(v.z - r2), l3 = bf16_rn(v.w - r3);
  ushort4 hv; hv.x = h0; hv.y = h1; hv.z = h2; hv.w = h3;
  ushort4 lv; lv.x = l0; lv.y = l1; lv.z = l2; lv.w = l3;
  *(ushort4*)(hi + idx) = hv;
  *(ushort4*)(lo + idx) = lv;
}

// ---------------------------------------------------------------------------
// Kernel 2 (MFMA): scores + top-1-over-heads mask + z = sum(exp(masked)).
// (unchanged from round 5)
// ---------------------------------------------------------------------------
__global__ __launch_bounds__(256) void k_scores_mfma(
    const ushort_t* __restrict__ Qh, const ushort_t* __restrict__ Ql,
    const ushort_t* __restrict__ Kh, const ushort_t* __restrict__ Kl,
    float* __restrict__ probs, float* __restrict__ st_m,
    float* __restrict__ st_z) {
  __shared__ __align__(16) uint4 kh_s[64 * 32];
  __shared__ __align__(16) uint4 kl_s[64 * 32];
  const int tid = threadIdx.x;
  const int w = tid >> 6, lane = tid & 63;
  const int li = lane & 15, kg = lane >> 4;
  const int i0 = blockIdx.x * 64;
  const int js = blockIdx.y;
  const int b  = blockIdx.z;
  const int jbase = js * 576;

  s8v ahi[8], alo[8];
  {
    const ushort_t* qh = Qh + ((size_t)b * S_TOT + i0 + w * 16 + li) * C_ + kg * 8;
    const ushort_t* ql = Ql + ((size_t)b * S_TOT + i0 + w * 16 + li) * C_ + kg * 8;
#pragma unroll
    for (int h = 0; h < 8; ++h) {
      ahi[h] = __builtin_bit_cast(s8v, *(const uint4*)(qh + h * 32));
      alo[h] = __builtin_bit_cast(s8v, *(const uint4*)(ql + h * 32));
    }
  }

  float zacc[4][8];
#pragma unroll
  for (int r = 0; r < 4; ++r)
#pragma unroll
    for (int h = 0; h < 8; ++h) zacc[r][h] = 0.f;

  for (int jt = 0; jt < 9; ++jt) {
    const int j0 = jbase + jt * 64;
    __syncthreads();
    for (int e = tid; e < 2048; e += 256) {
      int r = e >> 5, c = e & 31;
      size_t goff = ((size_t)b * S_TOT + j0 + r) * C_ + c * 8;
      int cs = c ^ (r & 7);
      kh_s[r * 32 + cs] = *(const uint4*)(Kh + goff);
      kl_s[r * 32 + cs] = *(const uint4*)(Kl + goff);
    }
    __syncthreads();

#pragma unroll
    for (int jsub = 0; jsub < 4; ++jsub) {
      const int rj = jsub * 16 + li;
      f32x4 sc[8];
#pragma unroll
      for (int h = 0; h < 8; ++h) {
        const int cs = (h * 4 + kg) ^ (rj & 7);
        s8v bhi = __builtin_bit_cast(s8v, kh_s[rj * 32 + cs]);
        s8v blo = __builtin_bit_cast(s8v, kl_s[rj * 32 + cs]);
        f32x4 acc = {0.f, 0.f, 0.f, 0.f};
        acc = __builtin_amdgcn_mfma_f32_16x16x32_bf16(ahi[h], bhi, acc, 0, 0, 0);
        acc = __builtin_amdgcn_mfma_f32_16x16x32_bf16(ahi[h], blo, acc, 0, 0, 0);
        acc = __builtin_amdgcn_mfma_f32_16x16x32_bf16(alo[h], bhi, acc, 0, 0, 0);
        sc[h] = acc;
      }
      const int jcol = j0 + jsub * 16 + li;
#pragma unroll
      for (int reg = 0; reg < 4; ++reg) {
        float s8_[8];
        float thr = -1e30f;
#pragma unroll
        for (int h = 0; h < 8; ++h) {
          s8_[h] = sc[h][reg] * INV_SQRT_DH;
          thr = fmaxf(thr, s8_[h]);
        }
        const int i = i0 + w * 16 + kg * 4 + reg;
#pragma unroll
        for (int h = 0; h < 8; ++h) {
          float mv = s8_[h] < thr ? -1e18f : s8_[h];
          probs[((size_t)((b * 8 + h) * S_TOT + i)) * S_TOT + jcol] = mv;
          zacc[reg][h] += __expf(mv);
        }
      }
    }
  }

#pragma unroll
  for (int reg = 0; reg < 4; ++reg) {
#pragma unroll
    for (int h = 0; h < 8; ++h) {
      float z = zacc[reg][h];
      z += __shfl_xor(z, 1);
      z += __shfl_xor(z, 2);
      z += __shfl_xor(z, 4);
      z += __shfl_xor(z, 8);
      if (li == 0) {
        const int i = i0 + w * 16 + kg * 4 + reg;
        size_t sidx = ((size_t)(js * B_ + b) * HEADS_ + h) * S_TOT + i;
        st_z[sidx] = z;
        st_m[sidx] = 0.f;
      }
    }
  }
}

// ---------------------------------------------------------------------------
// Kernel 3 (v3): probs finalize (in-place) + partial ctx = probs @ V.
// grid (36 i-tiles, 8 h, 6 = jc*2+b) = 1728 blocks, block 256 (4 waves).
// Each block covers 768 j's (12 tiles of 64); partial ctx -> part[jc].
// ---------------------------------------------------------------------------
__global__ __launch_bounds__(256) void k_pv2(const float* __restrict__ Vp,
                                             const float* __restrict__ st_m,
                                             const float* __restrict__ st_z,
                                             float* __restrict__ probs,
                                             float* __restrict__ part0,
                                             float* __restrict__ part1,
                                             float* __restrict__ part2) {
  __shared__ __align__(16) float p_s[64 * 64];   // 16 KB, quad-swizzled
  __shared__ __align__(16) float v_s[64 * 40];   // 10 KB (also reduce buffer)
  __shared__ float row_m[64], row_iz[64];
  const int tid = threadIdx.x;
  const int w = tid >> 6, lane = tid & 63;
  const int ig = lane & 7;
  const int dg = (lane >> 3) & 3;
  const int jg_w = lane >> 5;
  const int jg = w * 2 + jg_w;        // 0..7
  const int i0 = blockIdx.x * 64;
  const int h  = blockIdx.y;
  const int z  = blockIdx.z;
  const int b  = z & 1;
  const int jc = z >> 1;              // 0..2
  float* part = (jc == 0) ? part0 : ((jc == 1) ? part1 : part2);

  if (tid < 64) {
    const int i = i0 + tid;
    float mm[4], zz[4];
#pragma unroll
    for (int js = 0; js < 4; ++js) {
      size_t sidx = ((size_t)(js * B_ + b) * HEADS_ + h) * S_TOT + i;
      mm[js] = st_m[sidx];
      zz[js] = st_z[sidx];
    }
    float M = fmaxf(fmaxf(mm[0], mm[1]), fmaxf(mm[2], mm[3]));
    float Z = zz[0] * __expf(mm[0] - M) + zz[1] * __expf(mm[1] - M) +
              zz[2] * __expf(mm[2] - M) + zz[3] * __expf(mm[3] - M);
    if (Z == 0.f) {                   // fully-masked row: uniform (ref behavior)
      row_m[tid] = -1e18f;
      row_iz[tid] = 1.0f / (float)S_TOT;
    } else {
      row_m[tid] = M;
      row_iz[tid] = 1.0f / Z;
    }
  }
  __syncthreads();

  float4 acc[8][2];
#pragma unroll
  for (int ii = 0; ii < 8; ++ii)
#pragma unroll
    for (int dq = 0; dq < 2; ++dq) acc[ii][dq] = make_float4(0.f, 0.f, 0.f, 0.f);

  float* pbase = probs + ((size_t)(b * 8 + h) * S_TOT + i0) * S_TOT;
  const float* vbase = Vp + (size_t)b * S_TOT * C_ + h * 32;

  const int jlo = jc * 768, jhi = jlo + 768;
  for (int j0 = jlo; j0 < jhi; j0 += 64) {
#pragma unroll
    for (int k = 0; k < 4; ++k) {
      int e = tid + k * 256;
      int r = e >> 4, c4 = e & 15;
      float* gp = pbase + (size_t)r * S_TOT + j0 + c4 * 4;
      float4 sv = *(const float4*)gp;
      float M = row_m[r], iz = row_iz[r];
      float4 p;
      p.x = __expf(sv.x - M) * iz;
      p.y = __expf(sv.y - M) * iz;
      p.z = __expf(sv.z - M) * iz;
      p.w = __expf(sv.w - M) * iz;
      *(float4*)gp = p;
      int c4s = c4 ^ ((r >> 3) & 7);
      *(float4*)&p_s[r * 64 + c4s * 4] = p;
    }
#pragma unroll
    for (int k = 0; k < 2; ++k) {
      int e = tid + k * 256;
      int j = e >> 3, d4 = e & 7;
      float4 v = *(const float4*)(vbase + (size_t)(j0 + j) * C_ + d4 * 4);
      *(float4*)&v_s[j * 40 + d4 * 4] = v;
    }
    __syncthreads();

#pragma unroll
    for (int jq4 = 0; jq4 < 2; ++jq4) {
      float4 vv[4][2];
#pragma unroll
      for (int jj = 0; jj < 4; ++jj) {
        const float* vp = &v_s[(jg * 8 + jq4 * 4 + jj) * 40 + dg * 8];
        vv[jj][0] = *(const float4*)vp;
        vv[jj][1] = *(const float4*)(vp + 4);
      }
#pragma unroll
      for (int ii = 0; ii < 8; ++ii) {
        int cq = (2 * jg + jq4) ^ ig;
        float4 p4 = *(const float4*)&p_s[(ig * 8 + ii) * 64 + cq * 4];
#pragma unroll
        for (int dq = 0; dq < 2; ++dq) {
          float4 a = acc[ii][dq];
          a.x = fmaf(p4.x, vv[0][dq].x, fmaf(p4.y, vv[1][dq].x, fmaf(p4.z, vv[2][dq].x, fmaf(p4.w, vv[3][dq].x, a.x))));
          a.y = fmaf(p4.x, vv[0][dq].y, fmaf(p4.y, vv[1][dq].y, fmaf(p4.z, vv[2][dq].y, fmaf(p4.w, vv[3][dq].y, a.y))));
          a.z = fmaf(p4.x, vv[0][dq].z, fmaf(p4.y, vv[1][dq].z, fmaf(p4.z, vv[2][dq].z, fmaf(p4.w, vv[3][dq].z, a.z))));
          a.w = fmaf(p4.x, vv[0][dq].w, fmaf(p4.y, vv[1][dq].w, fmaf(p4.z, vv[2][dq].w, fmaf(p4.w, vv[3][dq].w, a.w))));
          acc[ii][dq] = a;
        }
      }
    }
    __syncthreads();
  }

#pragma unroll
  for (int ii = 0; ii < 8; ++ii)
#pragma unroll
    for (int dq = 0; dq < 2; ++dq) {
      acc[ii][dq].x += __shfl_xor(acc[ii][dq].x, 32);
      acc[ii][dq].y += __shfl_xor(acc[ii][dq].y, 32);
      acc[ii][dq].z += __shfl_xor(acc[ii][dq].z, 32);
      acc[ii][dq].w += __shfl_xor(acc[ii][dq].w, 32);
    }
  for (int r = 0; r < 4; ++r) {
    __syncthreads();
    if (w == r && jg_w == 0) {
#pragma unroll
      for (int ii = 0; ii < 8; ++ii)
#pragma unroll
        for (int dq = 0; dq < 2; ++dq) {
          float4* dst = (float4*)&v_s[(ig * 8 + ii) * 40 + dg * 8 + dq * 4];
          if (r == 0) *dst = acc[ii][dq];
          else {
            float4 o = *dst;
            o.x += acc[ii][dq].x; o.y += acc[ii][dq].y;
            o.z += acc[ii][dq].z; o.w += acc[ii][dq].w;
            *dst = o;
          }
        }
    }
  }
  __syncthreads();

#pragma unroll
  for (int t = 0; t < 8; ++t) {
    int idx = tid + t * 256;
    int i = idx & 63, d = idx >> 6;
    part[((size_t)(b * 256 + h * 32 + d)) * S_TOT + i0 + i] = v_s[i * 40 + d];
  }
}

// ---------------------------------------------------------------------------
// Kernel 3b: ctx = part0 + part1 + part2 (elementwise, float4)
// ---------------------------------------------------------------------------
__global__ __launch_bounds__(256) void k_pv_red(const float* __restrict__ p0,
                                                const float* __restrict__ p1,
                                                const float* __restrict__ p2,
                                                float* __restrict__ ctx) {
  size_t i4 = ((size_t)blockIdx.x * 256 + threadIdx.x) * 4;
  float4 a = *(const float4*)(p0 + i4);
  float4 b = *(const float4*)(p1 + i4);
  float4 c = *(const float4*)(p2 + i4);
  float4 o;
  o.x = a.x + b.x + c.x; o.y = a.y + b.y + c.y;
  o.z = a.z + b.z + c.z; o.w = a.w + b.w + c.w;
  *(float4*)(ctx + i4) = o;
}

// ---------------------------------------------------------------------------
// Kernel 4a: repack conv weights W[co][ci][3][3] -> Wt[ci][k][co]
// ---------------------------------------------------------------------------
__global__ __launch_bounds__(256) void k_repackW(const float* __restrict__ W,
                                                 float* __restrict__ Wt) {
  const int ci = blockIdx.x;
  const int k  = blockIdx.y;
  const int co = threadIdx.x;
  Wt[((size_t)ci * 9 + k) * 256 + co] = W[((size_t)co * 256 + ci) * 9 + k];
}

// ---------------------------------------------------------------------------
// Kernel 4b (v4): 3x3 SAME conv, ci-split across 2 blocks -> partials.
// grid (8 co-tiles, 48 rows, 4 = b*2+chalf) = 1536 blocks, block 256.
// Per s-step: 8 ci staged (W 10.1KB + in 5.25KB LDS); thread = cog(8 co-quads)
// x colg(4 x 12px) x cig(8 ci); inner loop ky-major, single 16-float row buf
// (VGPR ~90 -> 5 waves/SIMD). Cross-cig reduce -> partial write (no bias/act).
// ---------------------------------------------------------------------------
__global__ __launch_bounds__(256) void k_conv4(const float* __restrict__ in,
                                               const float* __restrict__ Wt,
                                               float* __restrict__ part0,
                                               float* __restrict__ part1) {
  __shared__ __align__(16) float w_s[8 * 9 * 36];    // 10.1 KB (reused as red)
  __shared__ __align__(16) float in_s[8 * 3 * 56];   // 5.25 KB
  const int tid = threadIdx.x;
  const int w = tid >> 6, lane = tid & 63;
  const int cog  = lane & 7;
  const int colg = (lane >> 3) & 3;
  const int cig  = tid >> 5;          // 0..7
  const int co0 = blockIdx.x * 32;
  const int row = blockIdx.y;
  const int z   = blockIdx.z;
  const int b = z >> 1, chalf = z & 1;
  float* part = (chalf == 0) ? part0 : part1;

  // zero halo cols {0..4, 53..55} for all 24 (ci,r) rows
  for (int e = tid; e < 24 * 8; e += 256) {
    int rr_ = e >> 3, c = e & 7;
    in_s[rr_ * 56 + (c < 5 ? c : 48 + c)] = 0.f;
  }

  float4 acc[12];
#pragma unroll
  for (int p = 0; p < 12; ++p) acc[p] = make_float4(0.f, 0.f, 0.f, 0.f);

  for (int s = 0; s < 16; ++s) {
    __syncthreads();
    // stage W: 8 ci x 9 k x 32 co = 576 float4
    for (int e = tid; e < 576; e += 256) {
      int coq = e & 7, t = e >> 3;
      int k = t % 9, ci = t / 9;
      float4 v = *(const float4*)(Wt + (((size_t)(chalf * 128 + s * 8 + ci) * 9 + k) * 256 + co0 + coq * 4));
      *(float4*)&w_s[(ci * 9 + k) * 36 + coq * 4] = v;
    }
    // stage input: 8 ci x 3 rows x 48 cols (scalar, coalesced)
    for (int e = tid; e < 1152; e += 256) {
      int col = e % 48; int t = e / 48;
      int r = t % 3; int ci = t / 3;
      int gr = row - 1 + r;
      float v = 0.f;
      if (gr >= 0 && gr < 48)
        v = in[((size_t)(b * 256 + chalf * 128 + s * 8 + ci) * 48 + gr) * 48 + col];
      in_s[(ci * 3 + r) * 56 + 5 + col] = v;
    }
    __syncthreads();

#pragma unroll
    for (int ky = 0; ky < 3; ++ky) {
      float rr[16];
      const float* ib = &in_s[(cig * 3 + ky) * 56 + 12 * colg + 4];
      *(float4*)&rr[0]  = *(const float4*)&ib[0];
      *(float4*)&rr[4]  = *(const float4*)&ib[4];
      *(float4*)&rr[8]  = *(const float4*)&ib[8];
      *(float4*)&rr[12] = *(const float4*)&ib[12];
#pragma unroll
      for (int kx = 0; kx < 3; ++kx) {
        float4 w4 = *(const float4*)&w_s[(cig * 9 + ky * 3 + kx) * 36 + cog * 4];
#pragma unroll
        for (int p = 0; p < 12; ++p) {
          float rv = rr[p + kx];
          acc[p].x = fmaf(rv, w4.x, acc[p].x);
          acc[p].y = fmaf(rv, w4.y, acc[p].y);
          acc[p].z = fmaf(rv, w4.z, acc[p].z);
          acc[p].w = fmaf(rv, w4.w, acc[p].w);
        }
      }
    }
  }

  // reduce across cig: in-wave half pair (lane^32), then 4 wave-rounds
#pragma unroll
  for (int p = 0; p < 12; ++p) {
    acc[p].x += __shfl_xor(acc[p].x, 32);
    acc[p].y += __shfl_xor(acc[p].y, 32);
    acc[p].z += __shfl_xor(acc[p].z, 32);
    acc[p].w += __shfl_xor(acc[p].w, 32);
  }
  float* red = w_s;   // [48 px][36]
  for (int r = 0; r < 4; ++r) {
    __syncthreads();
    if (w == r && (lane >> 5) == 0) {
#pragma unroll
      for (int p = 0; p < 12; ++p) {
        float4* dst = (float4*)&red[(colg * 12 + p) * 36 + cog * 4];
        if (r == 0) *dst = acc[p];
        else {
          float4 o = *dst;
          o.x += acc[p].x; o.y += acc[p].y; o.z += acc[p].z; o.w += acc[p].w;
          *dst = o;
        }
      }
    }
  }
  __syncthreads();

  for (int e = tid; e < 1536; e += 256) {
    int col = e % 48, co_l = e / 48;
    part[((size_t)(b * 256 + co0 + co_l) * 48 + row) * 48 + col] = red[col * 36 + co_l];
  }
}

// ---------------------------------------------------------------------------
// Kernel 4c: out = act(part0 + part1 + bias)  (SELU optional)
// ---------------------------------------------------------------------------
template<bool DO_SELU>
__global__ __launch_bounds__(256) void k_act(const float* __restrict__ p0,
                                             const float* __restrict__ p1,
                                             const float* __restrict__ bias,
                                             float* __restrict__ out) {
  size_t i4 = ((size_t)blockIdx.x * 256 + threadIdx.x) * 4;
  float4 a = *(const float4*)(p0 + i4);
  float4 b = *(const float4*)(p1 + i4);
  int co = (int)((i4 / (size_t)S_TOT) & 255);
  float bi = bias[co];
  float y[4] = {a.x + b.x + bi, a.y + b.y + bi, a.z + b.z + bi, a.w + b.w + bi};
  float4 o;
#pragma unroll
  for (int q = 0; q < 4; ++q) {
    float v = y[q];
    if (DO_SELU)
      v = 1.0507009873554805f * (v > 0.f ? v : 1.6732632423543772f * expm1f(v));
    ((float*)&o)[q] = v;
  }
  *(float4*)(out + i4) = o;
}

// ---------------------------------------------------------------------------
extern "C" void kernel_launch(void* const* d_in, const int* in_sizes, int n_in,
                              void* d_out, int out_size, void* d_ws, size_t ws_size,
                              hipStream_t stream) {
  const float* x   = (const float*)d_in[0];
  const float* ref = (const float*)d_in[1];
  const float* qW1 = (const float*)d_in[2];
  const float* qb1 = (const float*)d_in[3];
  const float* qW2 = (const float*)d_in[4];
  const float* qb2 = (const float*)d_in[5];
  const float* kW1 = (const float*)d_in[6];
  const float* kb1 = (const float*)d_in[7];
  const float* kW2 = (const float*)d_in[8];
  const float* kb2 = (const float*)d_in[9];
  const float* vW1 = (const float*)d_in[10];
  const float* vb1 = (const float*)d_in[11];
  const float* vW2 = (const float*)d_in[12];
  const float* vb2 = (const float*)d_in[13];
  const float* c1W = (const float*)d_in[14];
  const float* c1b = (const float*)d_in[15];
  const float* c2W = (const float*)d_in[16];
  const float* c2b = (const float*)d_in[17];

  float* out = (float*)d_out;
  float* probs = out + (size_t)B_ * C_ * S_TOT;       // [B][H][S][S]
  float* ws = (float*)d_ws;
  const size_t BSC = (size_t)B_ * S_TOT * C_;         // 1,179,648
  const size_t STATS = (size_t)4 * B_ * HEADS_ * S_TOT;
  const size_t WTSZ = (size_t)256 * 9 * 256;

  float* Qb  = ws;
  float* Kb  = Qb + BSC;
  float* Vb  = Kb + BSC;
  float* Ht  = Vb + BSC;
  float* stm = Ht + BSC;
  float* stz = stm + STATS;
  float* ctx = stz + STATS;
  float* tmp1 = ctx + BSC;
  float* Wt1 = tmp1 + BSC;
  float* Wt2 = Wt1 + WTSZ;

  // bf16 split planes: Q planes in Ht (free after MLPs), K planes in Qb.
  ushort_t* QhP = (ushort_t*)Ht;
  ushort_t* QlP = QhP + BSC;
  ushort_t* KhP = (ushort_t*)Qb;
  ushort_t* KlP = KhP + BSC;

  // pv partials reuse buffers dead after scores: Kb (K f32), Ht (Q planes),
  // Qb (K planes). conv partials reuse Kb/Qb (dead after pv_red).
  float* Pv0 = Kb;
  float* Pv1 = Ht;
  float* Pv2 = Qb;
  float* Cp0 = Kb;
  float* Cp1 = Qb;

  dim3 blk(256);
  k_repackW<<<dim3(256, 9), blk, 0, stream>>>(c1W, Wt1);
  k_repackW<<<dim3(256, 9), blk, 0, stream>>>(c2W, Wt2);

  dim3 gmlp(72, B_);
  k_mlp<0><<<gmlp, blk, 0, stream>>>(x,   qW1, qb1, Ht);
  k_mlp<1><<<gmlp, blk, 0, stream>>>(Ht,  qW2, qb2, Qb);
  k_mlp<0><<<gmlp, blk, 0, stream>>>(ref, kW1, kb1, Ht);
  k_mlp<1><<<gmlp, blk, 0, stream>>>(Ht,  kW2, kb2, Kb);
  k_mlp<0><<<gmlp, blk, 0, stream>>>(ref, vW1, vb1, Ht);
  k_mlp<1><<<gmlp, blk, 0, stream>>>(Ht,  vW2, vb2, Vb);

  const int nsplit = (int)(BSC / 4 / 256);            // 1152 blocks
  k_split<<<dim3(nsplit), blk, 0, stream>>>(Qb, QhP, QlP);  // Q -> Ht space
  k_split<<<dim3(nsplit), blk, 0, stream>>>(Kb, KhP, KlP);  // K -> Qb space

  k_scores_mfma<<<dim3(36, 4, B_), blk, 0, stream>>>(QhP, QlP, KhP, KlP,
                                                     probs, stm, stz);

  k_pv2<<<dim3(36, 8, 6), blk, 0, stream>>>(Vb, stm, stz, probs,
                                            Pv0, Pv1, Pv2);
  k_pv_red<<<dim3((int)(BSC / 1024)), blk, 0, stream>>>(Pv0, Pv1, Pv2, ctx);

  k_conv4<<<dim3(8, 48, 4), blk, 0, stream>>>(ctx, Wt1, Cp0, Cp1);
  k_act<true ><<<dim3((int)(BSC / 1024)), blk, 0, stream>>>(Cp0, Cp1, c1b, tmp1);
  k_conv4<<<dim3(8, 48, 4), blk, 0, stream>>>(tmp1, Wt2, Cp0, Cp1);
  k_act<false><<<dim3((int)(BSC / 1024)), blk, 0, stream>>>(Cp0, Cp1, c2b, out);
}

// Round 7
// 983.524 us; speedup vs baseline: 1.1304x; 1.1304x over previous
//
#include <hip/hip_runtime.h>
#include <hip/hip_bf16.h>

typedef unsigned short ushort_t;
typedef short s8v __attribute__((ext_vector_type(8)));   // 8 bf16 bit-patterns
typedef float f32x4 __attribute__((ext_vector_type(4)));

// Problem constants
constexpr int B_ = 2;
constexpr int C_ = 256;
constexpr int S_TOT = 48 * 48;   // 2304
constexpr int HEADS_ = 8;
#define INV_SQRT_DH 0.17677669529663688f

// ---------------------------------------------------------------------------
// Kernel 1: MLP layer  out[b][s][co] = relu( sum_ci in[b][s][ci]*W[ci][co] + b )
// ---------------------------------------------------------------------------
template<int IN_MODE>
__global__ __launch_bounds__(256) void k_mlp(const float* __restrict__ in,
                                             const float* __restrict__ Wm,
                                             const float* __restrict__ bias,
                                             float* __restrict__ out) {
  __shared__ __align__(16) float in_s[32][260];
  const int tid = threadIdx.x;
  const int s0 = blockIdx.x * 32;
  const int b  = blockIdx.y;

  if (IN_MODE == 0) {
    for (int idx = tid; idx < 32 * 256; idx += 256) {
      int ci = idx >> 5, r = idx & 31;
      in_s[r][ci] = in[((size_t)b * C_ + ci) * S_TOT + s0 + r];
    }
  } else {
    for (int idx = tid; idx < 32 * 256; idx += 256) {
      int r = idx >> 8, ci = idx & 255;
      in_s[r][ci] = in[((size_t)b * S_TOT + s0 + r) * C_ + ci];
    }
  }
  __syncthreads();

  const int co = tid;
  float acc[32];
#pragma unroll
  for (int r = 0; r < 32; ++r) acc[r] = 0.f;

  for (int c4 = 0; c4 < 64; ++c4) {
    const float w0 = Wm[(c4 * 4 + 0) * C_ + co];
    const float w1 = Wm[(c4 * 4 + 1) * C_ + co];
    const float w2 = Wm[(c4 * 4 + 2) * C_ + co];
    const float w3 = Wm[(c4 * 4 + 3) * C_ + co];
#pragma unroll
    for (int r = 0; r < 32; ++r) {
      float4 a = *(const float4*)&in_s[r][c4 * 4];
      acc[r] = fmaf(a.x, w0, fmaf(a.y, w1, fmaf(a.z, w2, fmaf(a.w, w3, acc[r]))));
    }
  }

  const float bi = bias[co];
#pragma unroll 4
  for (int r = 0; r < 32; ++r) {
    out[((size_t)b * S_TOT + s0 + r) * C_ + co] = fmaxf(acc[r] + bi, 0.f);
  }
}

// ---------------------------------------------------------------------------
// helpers: bf16 split
// ---------------------------------------------------------------------------
__device__ __forceinline__ ushort_t bf16_rn(float x) {
  unsigned u = __float_as_uint(x);
  return (ushort_t)((u + 0x7fffu + ((u >> 16) & 1u)) >> 16);
}

__global__ __launch_bounds__(256) void k_split(const float* __restrict__ in,
                                               ushort_t* __restrict__ hi,
                                               ushort_t* __restrict__ lo) {
  size_t idx = ((size_t)blockIdx.x * 256 + threadIdx.x) * 4;
  float4 v = *(const float4*)(in + idx);
  ushort_t h0 = bf16_rn(v.x), h1 = bf16_rn(v.y), h2 = bf16_rn(v.z), h3 = bf16_rn(v.w);
  float r0 = __uint_as_float((unsigned)h0 << 16);
  float r1 = __uint_as_float((unsigned)h1 << 16);
  float r2 = __uint_as_float((unsigned)h2 << 16);
  float r3 = __uint_as_float((unsigned)h3 << 16);
  ushort_t l0 = bf16_rn(v.x - r0), l1 = bf16_rn(v.y - r1);
  ushort_t l2 = bf16_rn(v.z - r2), l3 = bf16_rn(v.w - r3);
  ushort4 hv; hv.x = h0; hv.y = h1; hv.z = h2; hv.w = h3;
  ushort4 lv; lv.x = l0; lv.y = l1; lv.z = l2; lv.w = l3;
  *(ushort4*)(hi + idx) = hv;
  *(ushort4*)(lo + idx) = lv;
}

// ---------------------------------------------------------------------------
// Kernel 2 (MFMA): scores + top-1-over-heads mask + z = sum(exp(masked)).
// (unchanged from round 5 — verified layouts)
// ---------------------------------------------------------------------------
__global__ __launch_bounds__(256) void k_scores_mfma(
    const ushort_t* __restrict__ Qh, const ushort_t* __restrict__ Ql,
    const ushort_t* __restrict__ Kh, const ushort_t* __restrict__ Kl,
    float* __restrict__ probs, float* __restrict__ st_m,
    float* __restrict__ st_z) {
  __shared__ __align__(16) uint4 kh_s[64 * 32];
  __shared__ __align__(16) uint4 kl_s[64 * 32];
  const int tid = threadIdx.x;
  const int w = tid >> 6, lane = tid & 63;
  const int li = lane & 15, kg = lane >> 4;
  const int i0 = blockIdx.x * 64;
  const int js = blockIdx.y;
  const int b  = blockIdx.z;
  const int jbase = js * 576;

  s8v ahi[8], alo[8];
  {
    const ushort_t* qh = Qh + ((size_t)b * S_TOT + i0 + w * 16 + li) * C_ + kg * 8;
    const ushort_t* ql = Ql + ((size_t)b * S_TOT + i0 + w * 16 + li) * C_ + kg * 8;
#pragma unroll
    for (int h = 0; h < 8; ++h) {
      ahi[h] = __builtin_bit_cast(s8v, *(const uint4*)(qh + h * 32));
      alo[h] = __builtin_bit_cast(s8v, *(const uint4*)(ql + h * 32));
    }
  }

  float zacc[4][8];
#pragma unroll
  for (int r = 0; r < 4; ++r)
#pragma unroll
    for (int h = 0; h < 8; ++h) zacc[r][h] = 0.f;

  for (int jt = 0; jt < 9; ++jt) {
    const int j0 = jbase + jt * 64;
    __syncthreads();
    for (int e = tid; e < 2048; e += 256) {
      int r = e >> 5, c = e & 31;
      size_t goff = ((size_t)b * S_TOT + j0 + r) * C_ + c * 8;
      int cs = c ^ (r & 7);
      kh_s[r * 32 + cs] = *(const uint4*)(Kh + goff);
      kl_s[r * 32 + cs] = *(const uint4*)(Kl + goff);
    }
    __syncthreads();

#pragma unroll
    for (int jsub = 0; jsub < 4; ++jsub) {
      const int rj = jsub * 16 + li;
      f32x4 sc[8];
#pragma unroll
      for (int h = 0; h < 8; ++h) {
        const int cs = (h * 4 + kg) ^ (rj & 7);
        s8v bhi = __builtin_bit_cast(s8v, kh_s[rj * 32 + cs]);
        s8v blo = __builtin_bit_cast(s8v, kl_s[rj * 32 + cs]);
        f32x4 acc = {0.f, 0.f, 0.f, 0.f};
        acc = __builtin_amdgcn_mfma_f32_16x16x32_bf16(ahi[h], bhi, acc, 0, 0, 0);
        acc = __builtin_amdgcn_mfma_f32_16x16x32_bf16(ahi[h], blo, acc, 0, 0, 0);
        acc = __builtin_amdgcn_mfma_f32_16x16x32_bf16(alo[h], bhi, acc, 0, 0, 0);
        sc[h] = acc;
      }
      const int jcol = j0 + jsub * 16 + li;
#pragma unroll
      for (int reg = 0; reg < 4; ++reg) {
        float s8_[8];
        float thr = -1e30f;
#pragma unroll
        for (int h = 0; h < 8; ++h) {
          s8_[h] = sc[h][reg] * INV_SQRT_DH;
          thr = fmaxf(thr, s8_[h]);
        }
        const int i = i0 + w * 16 + kg * 4 + reg;
#pragma unroll
        for (int h = 0; h < 8; ++h) {
          float mv = s8_[h] < thr ? -1e18f : s8_[h];
          probs[((size_t)((b * 8 + h) * S_TOT + i)) * S_TOT + jcol] = mv;
          zacc[reg][h] += __expf(mv);
        }
      }
    }
  }

#pragma unroll
  for (int reg = 0; reg < 4; ++reg) {
#pragma unroll
    for (int h = 0; h < 8; ++h) {
      float z = zacc[reg][h];
      z += __shfl_xor(z, 1);
      z += __shfl_xor(z, 2);
      z += __shfl_xor(z, 4);
      z += __shfl_xor(z, 8);
      if (li == 0) {
        const int i = i0 + w * 16 + kg * 4 + reg;
        size_t sidx = ((size_t)(js * B_ + b) * HEADS_ + h) * S_TOT + i;
        st_z[sidx] = z;
        st_m[sidx] = 0.f;
      }
    }
  }
}

// ---------------------------------------------------------------------------
// Kernel 3 (v4): probs finalize + ctx = probs @ V, register-pipelined.
// grid (36 i-tiles, 8 h, 2 b) = 576 blocks, block 256 (4 waves).
// Per tile: ONE sync; tile t+1 global loads issue before tile t FMA phase.
// LDS double-buffered (p 16K x2 + V 10K x2 = 52 KB).
// ---------------------------------------------------------------------------
__global__ __launch_bounds__(256) void k_pv3(const float* __restrict__ Vp,
                                             const float* __restrict__ st_m,
                                             const float* __restrict__ st_z,
                                             float* __restrict__ probs,
                                             float* __restrict__ ctx) {
  __shared__ __align__(16) float p_s[2][64 * 64];
  __shared__ __align__(16) float v_s[2][64 * 40];
  __shared__ float row_m[64], row_iz[64];
  const int tid = threadIdx.x;
  const int w = tid >> 6, lane = tid & 63;
  const int ig = lane & 7;
  const int dg = (lane >> 3) & 3;
  const int jg_w = lane >> 5;
  const int jg = w * 2 + jg_w;
  const int i0 = blockIdx.x * 64;
  const int h  = blockIdx.y;
  const int b  = blockIdx.z;

  if (tid < 64) {
    const int i = i0 + tid;
    float mm[4], zz[4];
#pragma unroll
    for (int js = 0; js < 4; ++js) {
      size_t sidx = ((size_t)(js * B_ + b) * HEADS_ + h) * S_TOT + i;
      mm[js] = st_m[sidx];
      zz[js] = st_z[sidx];
    }
    float M = fmaxf(fmaxf(mm[0], mm[1]), fmaxf(mm[2], mm[3]));
    float Z = zz[0] * __expf(mm[0] - M) + zz[1] * __expf(mm[1] - M) +
              zz[2] * __expf(mm[2] - M) + zz[3] * __expf(mm[3] - M);
    if (Z == 0.f) {                   // fully-masked row: uniform (ref behavior)
      row_m[tid] = -1e18f;
      row_iz[tid] = 1.0f / (float)S_TOT;
    } else {
      row_m[tid] = M;
      row_iz[tid] = 1.0f / Z;
    }
  }

  float4 acc[8][2];
#pragma unroll
  for (int ii = 0; ii < 8; ++ii)
#pragma unroll
    for (int dq = 0; dq < 2; ++dq) acc[ii][dq] = make_float4(0.f, 0.f, 0.f, 0.f);

  float* pbase = probs + ((size_t)(b * 8 + h) * S_TOT + i0) * S_TOT;
  const float* vbase = Vp + (size_t)b * S_TOT * C_ + h * 32;

  // prologue: load tile 0 into regs
  float4 pr[4], vr[2];
#pragma unroll
  for (int k = 0; k < 4; ++k) {
    int e = tid + k * 256;
    int r = e >> 4, c4 = e & 15;
    pr[k] = *(const float4*)(pbase + (size_t)r * S_TOT + c4 * 4);
  }
#pragma unroll
  for (int k = 0; k < 2; ++k) {
    int e = tid + k * 256;
    int j = e >> 3, d4 = e & 7;
    vr[k] = *(const float4*)(vbase + (size_t)j * C_ + d4 * 4);
  }
  __syncthreads();   // row_m/row_iz ready

  for (int t = 0; t < 36; ++t) {
    const int j0 = t * 64;
    const int buf = t & 1;
    // finalize current regs -> global + LDS[buf]
#pragma unroll
    for (int k = 0; k < 4; ++k) {
      int e = tid + k * 256;
      int r = e >> 4, c4 = e & 15;
      float M = row_m[r], iz = row_iz[r];
      float4 p;
      p.x = __expf(pr[k].x - M) * iz;
      p.y = __expf(pr[k].y - M) * iz;
      p.z = __expf(pr[k].z - M) * iz;
      p.w = __expf(pr[k].w - M) * iz;
      *(float4*)(pbase + (size_t)r * S_TOT + j0 + c4 * 4) = p;
      int c4s = c4 ^ ((r >> 3) & 7);
      *(float4*)&p_s[buf][r * 64 + c4s * 4] = p;
    }
#pragma unroll
    for (int k = 0; k < 2; ++k) {
      int e = tid + k * 256;
      int j = e >> 3, d4 = e & 7;
      *(float4*)&v_s[buf][j * 40 + d4 * 4] = vr[k];
    }
    // issue next tile's loads (latency hides under FMA phase)
    if (t < 35) {
      const int j1 = j0 + 64;
#pragma unroll
      for (int k = 0; k < 4; ++k) {
        int e = tid + k * 256;
        int r = e >> 4, c4 = e & 15;
        pr[k] = *(const float4*)(pbase + (size_t)r * S_TOT + j1 + c4 * 4);
      }
#pragma unroll
      for (int k = 0; k < 2; ++k) {
        int e = tid + k * 256;
        int j = e >> 3, d4 = e & 7;
        vr[k] = *(const float4*)(vbase + (size_t)(j1 + j) * C_ + d4 * 4);
      }
    }
    __syncthreads();
    // FMA on LDS[buf]
#pragma unroll
    for (int jq4 = 0; jq4 < 2; ++jq4) {
      float4 vv[4][2];
#pragma unroll
      for (int jj = 0; jj < 4; ++jj) {
        const float* vp = &v_s[buf][(jg * 8 + jq4 * 4 + jj) * 40 + dg * 8];
        vv[jj][0] = *(const float4*)vp;
        vv[jj][1] = *(const float4*)(vp + 4);
      }
#pragma unroll
      for (int ii = 0; ii < 8; ++ii) {
        int cq = (2 * jg + jq4) ^ ig;
        float4 p4 = *(const float4*)&p_s[buf][(ig * 8 + ii) * 64 + cq * 4];
#pragma unroll
        for (int dq = 0; dq < 2; ++dq) {
          float4 a = acc[ii][dq];
          a.x = fmaf(p4.x, vv[0][dq].x, fmaf(p4.y, vv[1][dq].x, fmaf(p4.z, vv[2][dq].x, fmaf(p4.w, vv[3][dq].x, a.x))));
          a.y = fmaf(p4.x, vv[0][dq].y, fmaf(p4.y, vv[1][dq].y, fmaf(p4.z, vv[2][dq].y, fmaf(p4.w, vv[3][dq].y, a.y))));
          a.z = fmaf(p4.x, vv[0][dq].z, fmaf(p4.y, vv[1][dq].z, fmaf(p4.z, vv[2][dq].z, fmaf(p4.w, vv[3][dq].z, a.z))));
          a.w = fmaf(p4.x, vv[0][dq].w, fmaf(p4.y, vv[1][dq].w, fmaf(p4.z, vv[2][dq].w, fmaf(p4.w, vv[3][dq].w, a.w))));
          acc[ii][dq] = a;
        }
      }
    }
    // no second sync: next iter writes the OTHER buffer
  }

  __syncthreads();
#pragma unroll
  for (int ii = 0; ii < 8; ++ii)
#pragma unroll
    for (int dq = 0; dq < 2; ++dq) {
      acc[ii][dq].x += __shfl_xor(acc[ii][dq].x, 32);
      acc[ii][dq].y += __shfl_xor(acc[ii][dq].y, 32);
      acc[ii][dq].z += __shfl_xor(acc[ii][dq].z, 32);
      acc[ii][dq].w += __shfl_xor(acc[ii][dq].w, 32);
    }
  for (int r = 0; r < 4; ++r) {
    __syncthreads();
    if (w == r && jg_w == 0) {
#pragma unroll
      for (int ii = 0; ii < 8; ++ii)
#pragma unroll
        for (int dq = 0; dq < 2; ++dq) {
          float4* dst = (float4*)&v_s[0][(ig * 8 + ii) * 40 + dg * 8 + dq * 4];
          if (r == 0) *dst = acc[ii][dq];
          else {
            float4 o = *dst;
            o.x += acc[ii][dq].x; o.y += acc[ii][dq].y;
            o.z += acc[ii][dq].z; o.w += acc[ii][dq].w;
            *dst = o;
          }
        }
    }
  }
  __syncthreads();

#pragma unroll
  for (int t = 0; t < 8; ++t) {
    int idx = tid + t * 256;
    int i = idx & 63, d = idx >> 6;
    ctx[((size_t)(b * 256 + h * 32 + d)) * S_TOT + i0 + i] = v_s[0][i * 40 + d];
  }
}

// ---------------------------------------------------------------------------
// Kernel 4a: repack+split conv weights W[co][ci][3][3] -> Wh/Wl[tap][co][ci]
// grid (256 co, 9 tap), block 256 (ci)
// ---------------------------------------------------------------------------
__global__ __launch_bounds__(256) void k_repackW_split(const float* __restrict__ W,
                                                       ushort_t* __restrict__ Wh,
                                                       ushort_t* __restrict__ Wl) {
  const int co = blockIdx.x, tap = blockIdx.y, ci = threadIdx.x;
  float v = W[((size_t)co * 256 + ci) * 9 + tap];
  ushort_t h = bf16_rn(v);
  float r = __uint_as_float((unsigned)h << 16);
  ushort_t l = bf16_rn(v - r);
  size_t o = ((size_t)tap * 256 + co) * 256 + ci;
  Wh[o] = h;
  Wl[o] = l;
}

// ---------------------------------------------------------------------------
// Kernel 4b: 3x3 SAME conv as split-bf16 MFMA implicit GEMM.
// grid (8 co-tiles, 24 row-pairs, 2 b) = 384 blocks, block 256 = 4 waves.
// Wave w: co-group cg=w&1 (16 co), output row rw=w>>1 (y0+rw), 3 px-groups of 16.
// K-loop: 8 chunks of 32 ci; input staged transposed bf16 hi/lo
// [4 rows][50 x][40 ci-pad] (16B-aligned rows); A = W[tap][co][ci] hi/lo.
// Per chunk per wave: 9 taps x 3 xg x 3 MFMA(16x16x32 bf16).
// C-layout (verified via k_scores_mfma): co = kg*4+reg band, px = li.
// ---------------------------------------------------------------------------
template<bool DO_SELU>
__global__ __launch_bounds__(256) void k_conv_mfma(
    const float* __restrict__ in,          // [b][ci][48][48] f32
    const ushort_t* __restrict__ Wh, const ushort_t* __restrict__ Wl,
    const float* __restrict__ bias, float* __restrict__ out) {
  __shared__ __align__(16) ushort_t in_sh[4 * 50 * 40];
  __shared__ __align__(16) ushort_t in_sl[4 * 50 * 40];
  const int tid = threadIdx.x;
  const int w = tid >> 6, lane = tid & 63;
  const int li = lane & 15, kg = lane >> 4;
  const int cg = w & 1, rw = w >> 1;
  const int co0 = blockIdx.x * 32;
  const int y0  = blockIdx.y * 2;
  const int b   = blockIdx.z;

  // zero halo columns x_l = 0 and 49 (all 4 staged rows, ci 0..39), once
  for (int e = tid; e < 320; e += 256) {
    int sr = e / 80, rem = e % 80;
    int xl = (rem / 40) * 49, ci = rem % 40;
    in_sh[(sr * 50 + xl) * 40 + ci] = 0;
    in_sl[(sr * 50 + xl) * 40 + ci] = 0;
  }

  f32x4 acc[3];
#pragma unroll
  for (int xg = 0; xg < 3; ++xg) acc[xg] = (f32x4){0.f, 0.f, 0.f, 0.f};

  for (int c8 = 0; c8 < 8; ++c8) {
    __syncthreads();   // previous compute done (and zero-fill on first iter)
    // stage: [ci 32][sr 4][x4 12] float4 units, 6 per thread
#pragma unroll
    for (int u = 0; u < 6; ++u) {
      int idx = u * 256 + tid;          // 0..1535
      int rest = idx / 12;
      int x4 = idx - rest * 12;
      int sr = rest & 3, ci = rest >> 2;
      int gr = y0 - 1 + sr;
      float4 v = make_float4(0.f, 0.f, 0.f, 0.f);
      if (gr >= 0 && gr < 48)
        v = *(const float4*)(in + ((size_t)(b * 256 + c8 * 32 + ci) * 48 + gr) * 48 + x4 * 4);
      ushort_t* bh = &in_sh[(sr * 50 + x4 * 4 + 1) * 40 + ci];
      ushort_t* bl = &in_sl[(sr * 50 + x4 * 4 + 1) * 40 + ci];
      float c[4] = {v.x, v.y, v.z, v.w};
#pragma unroll
      for (int q = 0; q < 4; ++q) {
        ushort_t hq = bf16_rn(c[q]);
        float rq = __uint_as_float((unsigned)hq << 16);
        bh[q * 40] = hq;
        bl[q * 40] = bf16_rn(c[q] - rq);
      }
    }
    __syncthreads();

    // load A-frags for all 9 taps (global, L2-hot)
    s8v ah[9], al[9];
    {
      const ushort_t* wbh = Wh + ((size_t)(co0 + cg * 16 + li)) * 256 + c8 * 32 + kg * 8;
      const ushort_t* wbl = Wl + ((size_t)(co0 + cg * 16 + li)) * 256 + c8 * 32 + kg * 8;
#pragma unroll
      for (int tap = 0; tap < 9; ++tap) {
        ah[tap] = __builtin_bit_cast(s8v, *(const uint4*)(wbh + (size_t)tap * 65536));
        al[tap] = __builtin_bit_cast(s8v, *(const uint4*)(wbl + (size_t)tap * 65536));
      }
    }

#pragma unroll
    for (int ky = 0; ky < 3; ++ky) {
      const int srr = rw + ky;
#pragma unroll
      for (int kx = 0; kx < 3; ++kx) {
        const int tap = ky * 3 + kx;
#pragma unroll
        for (int xg = 0; xg < 3; ++xg) {
          const int xl = xg * 16 + li + kx;
          const ushort_t* bp = &in_sh[(srr * 50 + xl) * 40 + kg * 8];
          const ushort_t* bq = &in_sl[(srr * 50 + xl) * 40 + kg * 8];
          s8v bh = __builtin_bit_cast(s8v, *(const uint4*)bp);
          s8v bl = __builtin_bit_cast(s8v, *(const uint4*)bq);
          acc[xg] = __builtin_amdgcn_mfma_f32_16x16x32_bf16(ah[tap], bh, acc[xg], 0, 0, 0);
          acc[xg] = __builtin_amdgcn_mfma_f32_16x16x32_bf16(ah[tap], bl, acc[xg], 0, 0, 0);
          acc[xg] = __builtin_amdgcn_mfma_f32_16x16x32_bf16(al[tap], bh, acc[xg], 0, 0, 0);
        }
      }
    }
  }

  // epilogue: co = co0 + cg*16 + kg*4 + reg, px = (y0+rw)*48 + xg*16 + li
  const int orow = y0 + rw;
#pragma unroll
  for (int reg = 0; reg < 4; ++reg) {
    const int co = co0 + cg * 16 + kg * 4 + reg;
    const float bi = bias[co];
    float* op = out + ((size_t)(b * 256 + co) * 48 + orow) * 48 + li;
#pragma unroll
    for (int xg = 0; xg < 3; ++xg) {
      float y = acc[xg][reg] + bi;
      if (DO_SELU)
        y = 1.0507009873554805f * (y > 0.f ? y : 1.6732632423543772f * expm1f(y));
      op[xg * 16] = y;
    }
  }
}

// ---------------------------------------------------------------------------
extern "C" void kernel_launch(void* const* d_in, const int* in_sizes, int n_in,
                              void* d_out, int out_size, void* d_ws, size_t ws_size,
                              hipStream_t stream) {
  const float* x   = (const float*)d_in[0];
  const float* ref = (const float*)d_in[1];
  const float* qW1 = (const float*)d_in[2];
  const float* qb1 = (const float*)d_in[3];
  const float* qW2 = (const float*)d_in[4];
  const float* qb2 = (const float*)d_in[5];
  const float* kW1 = (const float*)d_in[6];
  const float* kb1 = (const float*)d_in[7];
  const float* kW2 = (const float*)d_in[8];
  const float* kb2 = (const float*)d_in[9];
  const float* vW1 = (const float*)d_in[10];
  const float* vb1 = (const float*)d_in[11];
  const float* vW2 = (const float*)d_in[12];
  const float* vb2 = (const float*)d_in[13];
  const float* c1W = (const float*)d_in[14];
  const float* c1b = (const float*)d_in[15];
  const float* c2W = (const float*)d_in[16];
  const float* c2b = (const float*)d_in[17];

  float* out = (float*)d_out;
  float* probs = out + (size_t)B_ * C_ * S_TOT;       // [B][H][S][S]
  float* ws = (float*)d_ws;
  const size_t BSC = (size_t)B_ * S_TOT * C_;         // 1,179,648
  const size_t STATS = (size_t)4 * B_ * HEADS_ * S_TOT;
  const size_t WTSZ = (size_t)256 * 9 * 256;          // floats-worth of space

  float* Qb  = ws;
  float* Kb  = Qb + BSC;
  float* Vb  = Kb + BSC;
  float* Ht  = Vb + BSC;
  float* stm = Ht + BSC;
  float* stz = stm + STATS;
  float* ctx = stz + STATS;
  float* tmp1 = ctx + BSC;
  float* Wt1 = tmp1 + BSC;
  float* Wt2 = Wt1 + WTSZ;

  // bf16 split planes: Q planes in Ht (free after MLPs), K planes in Qb.
  ushort_t* QhP = (ushort_t*)Ht;
  ushort_t* QlP = QhP + BSC;
  ushort_t* KhP = (ushort_t*)Qb;
  ushort_t* KlP = KhP + BSC;

  // conv weight split planes live in the Wt regions (exact fit)
  ushort_t* Wh1 = (ushort_t*)Wt1;
  ushort_t* Wl1 = Wh1 + WTSZ;
  ushort_t* Wh2 = (ushort_t*)Wt2;
  ushort_t* Wl2 = Wh2 + WTSZ;

  dim3 blk(256);
  k_repackW_split<<<dim3(256, 9), blk, 0, stream>>>(c1W, Wh1, Wl1);
  k_repackW_split<<<dim3(256, 9), blk, 0, stream>>>(c2W, Wh2, Wl2);

  dim3 gmlp(72, B_);
  k_mlp<0><<<gmlp, blk, 0, stream>>>(x,   qW1, qb1, Ht);
  k_mlp<1><<<gmlp, blk, 0, stream>>>(Ht,  qW2, qb2, Qb);
  k_mlp<0><<<gmlp, blk, 0, stream>>>(ref, kW1, kb1, Ht);
  k_mlp<1><<<gmlp, blk, 0, stream>>>(Ht,  kW2, kb2, Kb);
  k_mlp<0><<<gmlp, blk, 0, stream>>>(ref, vW1, vb1, Ht);
  k_mlp<1><<<gmlp, blk, 0, stream>>>(Ht,  vW2, vb2, Vb);

  const int nsplit = (int)(BSC / 4 / 256);            // 1152 blocks
  k_split<<<dim3(nsplit), blk, 0, stream>>>(Qb, QhP, QlP);  // Q -> Ht space
  k_split<<<dim3(nsplit), blk, 0, stream>>>(Kb, KhP, KlP);  // K -> Qb space

  k_scores_mfma<<<dim3(36, 4, B_), blk, 0, stream>>>(QhP, QlP, KhP, KlP,
                                                     probs, stm, stz);

  k_pv3<<<dim3(36, 8, B_), blk, 0, stream>>>(Vb, stm, stz, probs, ctx);

  k_conv_mfma<true ><<<dim3(8, 24, B_), blk, 0, stream>>>(ctx,  Wh1, Wl1, c1b, tmp1);
  k_conv_mfma<false><<<dim3(8, 24, B_), blk, 0, stream>>>(tmp1, Wh2, Wl2, c2b, out);
}

// Round 8
// 910.507 us; speedup vs baseline: 1.2211x; 1.0802x over previous
//
#include <hip/hip_runtime.h>
#include <hip/hip_bf16.h>

typedef unsigned short ushort_t;
typedef short s8v __attribute__((ext_vector_type(8)));      // 8 bf16 bit-patterns
typedef ushort_t u16x8 __attribute__((ext_vector_type(8))); // 8 ushorts (16B)
typedef float f32x4 __attribute__((ext_vector_type(4)));

// Problem constants
constexpr int B_ = 2;
constexpr int C_ = 256;
constexpr int S_TOT = 48 * 48;   // 2304
constexpr int HEADS_ = 8;
#define INV_SQRT_DH 0.17677669529663688f

// ---------------------------------------------------------------------------
// Kernel 1: MLP layer  out[b][s][co] = relu( sum_ci in[b][s][ci]*W[ci][co] + b )
// ---------------------------------------------------------------------------
template<int IN_MODE>
__global__ __launch_bounds__(256) void k_mlp(const float* __restrict__ in,
                                             const float* __restrict__ Wm,
                                             const float* __restrict__ bias,
                                             float* __restrict__ out) {
  __shared__ __align__(16) float in_s[32][260];
  const int tid = threadIdx.x;
  const int s0 = blockIdx.x * 32;
  const int b  = blockIdx.y;

  if (IN_MODE == 0) {
    for (int idx = tid; idx < 32 * 256; idx += 256) {
      int ci = idx >> 5, r = idx & 31;
      in_s[r][ci] = in[((size_t)b * C_ + ci) * S_TOT + s0 + r];
    }
  } else {
    for (int idx = tid; idx < 32 * 256; idx += 256) {
      int r = idx >> 8, ci = idx & 255;
      in_s[r][ci] = in[((size_t)b * S_TOT + s0 + r) * C_ + ci];
    }
  }
  __syncthreads();

  const int co = tid;
  float acc[32];
#pragma unroll
  for (int r = 0; r < 32; ++r) acc[r] = 0.f;

  for (int c4 = 0; c4 < 64; ++c4) {
    const float w0 = Wm[(c4 * 4 + 0) * C_ + co];
    const float w1 = Wm[(c4 * 4 + 1) * C_ + co];
    const float w2 = Wm[(c4 * 4 + 2) * C_ + co];
    const float w3 = Wm[(c4 * 4 + 3) * C_ + co];
#pragma unroll
    for (int r = 0; r < 32; ++r) {
      float4 a = *(const float4*)&in_s[r][c4 * 4];
      acc[r] = fmaf(a.x, w0, fmaf(a.y, w1, fmaf(a.z, w2, fmaf(a.w, w3, acc[r]))));
    }
  }

  const float bi = bias[co];
#pragma unroll 4
  for (int r = 0; r < 32; ++r) {
    out[((size_t)b * S_TOT + s0 + r) * C_ + co] = fmaxf(acc[r] + bi, 0.f);
  }
}

// ---------------------------------------------------------------------------
// helpers: bf16 split
// ---------------------------------------------------------------------------
__device__ __forceinline__ ushort_t bf16_rn(float x) {
  unsigned u = __float_as_uint(x);
  return (ushort_t)((u + 0x7fffu + ((u >> 16) & 1u)) >> 16);
}

__global__ __launch_bounds__(256) void k_split(const float* __restrict__ in,
                                               ushort_t* __restrict__ hi,
                                               ushort_t* __restrict__ lo) {
  size_t idx = ((size_t)blockIdx.x * 256 + threadIdx.x) * 4;
  float4 v = *(const float4*)(in + idx);
  ushort_t h0 = bf16_rn(v.x), h1 = bf16_rn(v.y), h2 = bf16_rn(v.z), h3 = bf16_rn(v.w);
  float r0 = __uint_as_float((unsigned)h0 << 16);
  float r1 = __uint_as_float((unsigned)h1 << 16);
  float r2 = __uint_as_float((unsigned)h2 << 16);
  float r3 = __uint_as_float((unsigned)h3 << 16);
  ushort_t l0 = bf16_rn(v.x - r0), l1 = bf16_rn(v.y - r1);
  ushort_t l2 = bf16_rn(v.z - r2), l3 = bf16_rn(v.w - r3);
  ushort4 hv; hv.x = h0; hv.y = h1; hv.z = h2; hv.w = h3;
  ushort4 lv; lv.x = l0; lv.y = l1; lv.z = l2; lv.w = l3;
  *(ushort4*)(hi + idx) = hv;
  *(ushort4*)(lo + idx) = lv;
}

// ---------------------------------------------------------------------------
// Kernel 1c: V [b][s][256] f32 -> transposed bf16 hi/lo planes [b][256][s]
// grid (36 s-tiles, 4 d-tiles, B), block 256. LDS 64x65 f32 tile.
// ---------------------------------------------------------------------------
__global__ __launch_bounds__(256) void k_splitT(const float* __restrict__ in,
                                                ushort_t* __restrict__ hiT,
                                                ushort_t* __restrict__ loT) {
  __shared__ __align__(16) float t_s[64][65];
  const int tid = threadIdx.x;
  const int s0 = blockIdx.x * 64;
  const int d0 = blockIdx.y * 64;
  const int b  = blockIdx.z;

#pragma unroll
  for (int k = 0; k < 16; ++k) {
    int idx = tid + k * 256;
    int r = idx >> 6, c = idx & 63;
    t_s[r][c] = in[((size_t)b * S_TOT + s0 + r) * C_ + d0 + c];
  }
  __syncthreads();
#pragma unroll
  for (int k = 0; k < 16; ++k) {
    int idx = tid + k * 256;
    int dr = idx >> 6, sc = idx & 63;
    float v = t_s[sc][dr];
    ushort_t h = bf16_rn(v);
    float rr = __uint_as_float((unsigned)h << 16);
    ushort_t l = bf16_rn(v - rr);
    size_t o = ((size_t)b * C_ + d0 + dr) * S_TOT + s0 + sc;
    hiT[o] = h;
    loT[o] = l;
  }
}

// ---------------------------------------------------------------------------
// Kernel 2 (MFMA): scores + top-1-over-heads mask; writes U = exp(masked)
// as bf16 (unnormalized probs) and per-row partial Z = sum of the ROUNDED
// u values (so probs = u * (1/Z) rows sum to exactly 1).
// grid (36 i-tiles, 4 j-chunks, B), block 256 = 4 waves.
// ---------------------------------------------------------------------------
__global__ __launch_bounds__(256) void k_scores_mfma(
    const ushort_t* __restrict__ Qh, const ushort_t* __restrict__ Ql,
    const ushort_t* __restrict__ Kh, const ushort_t* __restrict__ Kl,
    ushort_t* __restrict__ U, float* __restrict__ st_z) {
  __shared__ __align__(16) uint4 kh_s[64 * 32];
  __shared__ __align__(16) uint4 kl_s[64 * 32];
  const int tid = threadIdx.x;
  const int w = tid >> 6, lane = tid & 63;
  const int li = lane & 15, kg = lane >> 4;
  const int i0 = blockIdx.x * 64;
  const int js = blockIdx.y;
  const int b  = blockIdx.z;
  const int jbase = js * 576;

  s8v ahi[8], alo[8];
  {
    const ushort_t* qh = Qh + ((size_t)b * S_TOT + i0 + w * 16 + li) * C_ + kg * 8;
    const ushort_t* ql = Ql + ((size_t)b * S_TOT + i0 + w * 16 + li) * C_ + kg * 8;
#pragma unroll
    for (int h = 0; h < 8; ++h) {
      ahi[h] = __builtin_bit_cast(s8v, *(const uint4*)(qh + h * 32));
      alo[h] = __builtin_bit_cast(s8v, *(const uint4*)(ql + h * 32));
    }
  }

  float zacc[4][8];
#pragma unroll
  for (int r = 0; r < 4; ++r)
#pragma unroll
    for (int h = 0; h < 8; ++h) zacc[r][h] = 0.f;

  for (int jt = 0; jt < 9; ++jt) {
    const int j0 = jbase + jt * 64;
    __syncthreads();
    for (int e = tid; e < 2048; e += 256) {
      int r = e >> 5, c = e & 31;
      size_t goff = ((size_t)b * S_TOT + j0 + r) * C_ + c * 8;
      int cs = c ^ (r & 7);
      kh_s[r * 32 + cs] = *(const uint4*)(Kh + goff);
      kl_s[r * 32 + cs] = *(const uint4*)(Kl + goff);
    }
    __syncthreads();

#pragma unroll
    for (int jsub = 0; jsub < 4; ++jsub) {
      const int rj = jsub * 16 + li;
      f32x4 sc[8];
#pragma unroll
      for (int h = 0; h < 8; ++h) {
        const int cs = (h * 4 + kg) ^ (rj & 7);
        s8v bhi = __builtin_bit_cast(s8v, kh_s[rj * 32 + cs]);
        s8v blo = __builtin_bit_cast(s8v, kl_s[rj * 32 + cs]);
        f32x4 acc = {0.f, 0.f, 0.f, 0.f};
        acc = __builtin_amdgcn_mfma_f32_16x16x32_bf16(ahi[h], bhi, acc, 0, 0, 0);
        acc = __builtin_amdgcn_mfma_f32_16x16x32_bf16(ahi[h], blo, acc, 0, 0, 0);
        acc = __builtin_amdgcn_mfma_f32_16x16x32_bf16(alo[h], bhi, acc, 0, 0, 0);
        sc[h] = acc;
      }
      const int jcol = j0 + jsub * 16 + li;
#pragma unroll
      for (int reg = 0; reg < 4; ++reg) {
        float s8_[8];
        float thr = -1e30f;
#pragma unroll
        for (int h = 0; h < 8; ++h) {
          s8_[h] = sc[h][reg] * INV_SQRT_DH;
          thr = fmaxf(thr, s8_[h]);
        }
        const int i = i0 + w * 16 + kg * 4 + reg;
#pragma unroll
        for (int h = 0; h < 8; ++h) {
          float mv = s8_[h] < thr ? -1e18f : s8_[h];
          float uf = __expf(mv);            // 0 exactly when masked
          ushort_t ub = bf16_rn(uf);
          U[((size_t)((b * 8 + h) * S_TOT + i)) * S_TOT + jcol] = ub;
          zacc[reg][h] += __uint_as_float((unsigned)ub << 16);
        }
      }
    }
  }

#pragma unroll
  for (int reg = 0; reg < 4; ++reg) {
#pragma unroll
    for (int h = 0; h < 8; ++h) {
      float z = zacc[reg][h];
      z += __shfl_xor(z, 1);
      z += __shfl_xor(z, 2);
      z += __shfl_xor(z, 4);
      z += __shfl_xor(z, 8);
      if (li == 0) {
        const int i = i0 + w * 16 + kg * 4 + reg;
        size_t sidx = ((size_t)(js * B_ + b) * HEADS_ + h) * S_TOT + i;
        st_z[sidx] = z;
      }
    }
  }
}

// ---------------------------------------------------------------------------
// Kernel 3 (v5): probs = U * (1/Z) (f32 write) + ctx = (U @ V) * (1/Z),
// PV via bf16 MFMA (A=U, B=V^T hi/lo), K summed in-MFMA -> no reduction.
// grid (36 i-tiles, 8 h, 2 b) = 576 blocks, block 256 (4 waves).
// Wave w owns i-rows [w*16,w*16+16); per j-tile(64): 2 A-frags, 8 B-frags,
// 8 MFMA. Reg-prefetch pipeline (pv3-style), LDS double-buffered 32.5 KB.
// ---------------------------------------------------------------------------
__global__ __launch_bounds__(256) void k_pv4(const ushort_t* __restrict__ U,
                                             const float* __restrict__ st_z,
                                             const ushort_t* __restrict__ VhT,
                                             const ushort_t* __restrict__ VlT,
                                             float* __restrict__ probs,
                                             float* __restrict__ ctx) {
  __shared__ __align__(16) ushort_t u_s[2][64 * 64];   // 8 KB x2
  __shared__ __align__(16) ushort_t vh_s[2][32 * 64];  // 4 KB x2
  __shared__ __align__(16) ushort_t vl_s[2][32 * 64];  // 4 KB x2
  __shared__ float row_iz[64];
  __shared__ int   row_sub[64];
  const int tid = threadIdx.x;
  const int w = tid >> 6, lane = tid & 63;
  const int li = lane & 15, kg = lane >> 4;
  const int i0 = blockIdx.x * 64;
  const int h  = blockIdx.y;
  const int b  = blockIdx.z;

  if (tid < 64) {
    const int i = i0 + tid;
    float Z = 0.f;
#pragma unroll
    for (int js = 0; js < 4; ++js)
      Z += st_z[((size_t)(js * B_ + b) * HEADS_ + h) * S_TOT + i];
    if (Z == 0.f) { row_iz[tid] = 1.0f / (float)S_TOT; row_sub[tid] = 1; }
    else          { row_iz[tid] = 1.0f / Z;            row_sub[tid] = 0; }
  }

  const ushort_t* ub = U + ((size_t)((b * 8 + h) * S_TOT + i0)) * S_TOT;
  float* pb = probs + ((size_t)((b * 8 + h) * S_TOT + i0)) * S_TOT;
  const ushort_t* vhb = VhT + ((size_t)(b * C_ + h * 32)) * S_TOT;
  const ushort_t* vlb = VlT + ((size_t)(b * C_ + h * 32)) * S_TOT;

  // per-thread staging maps
  const int r0_  = tid >> 3,        c8_0 = tid & 7;          // U part 0
  const int r1_  = (tid + 256) >> 3, c8_1 = tid & 7;         // U part 1
  const int dr_  = tid >> 3, c8v = tid & 7;                  // V (32 rows)
  const size_t uo0 = (size_t)r0_ * S_TOT + c8_0 * 8;
  const size_t uo1 = (size_t)r1_ * S_TOT + c8_1 * 8;
  const size_t vo  = (size_t)(dr_ & 31) * S_TOT + c8v * 8;

  // accumulators: per wave 16i x 32d -> 2 dhalf x f32x4
  f32x4 acc[2];
  acc[0] = (f32x4){0.f, 0.f, 0.f, 0.f};
  acc[1] = (f32x4){0.f, 0.f, 0.f, 0.f};

  // prologue: prefetch tile 0
  u16x8 ur0 = *(const u16x8*)(ub + uo0);
  u16x8 ur1 = *(const u16x8*)(ub + uo1);
  u16x8 vhr = *(const u16x8*)(vhb + vo);
  u16x8 vlr = *(const u16x8*)(vlb + vo);
  __syncthreads();   // stats ready

  for (int t = 0; t < 36; ++t) {
    const int j0 = t * 64;
    const int buf = t & 1;

    // process U regs -> probs write + LDS (with Z==0 substitution)
    {
      u16x8 uu = ur0;
      if (row_sub[r0_]) uu = (u16x8){0x3F80,0x3F80,0x3F80,0x3F80,0x3F80,0x3F80,0x3F80,0x3F80};
      float iz = row_iz[r0_];
      float4 p0, p1;
      p0.x = __uint_as_float((unsigned)uu[0] << 16) * iz;
      p0.y = __uint_as_float((unsigned)uu[1] << 16) * iz;
      p0.z = __uint_as_float((unsigned)uu[2] << 16) * iz;
      p0.w = __uint_as_float((unsigned)uu[3] << 16) * iz;
      p1.x = __uint_as_float((unsigned)uu[4] << 16) * iz;
      p1.y = __uint_as_float((unsigned)uu[5] << 16) * iz;
      p1.z = __uint_as_float((unsigned)uu[6] << 16) * iz;
      p1.w = __uint_as_float((unsigned)uu[7] << 16) * iz;
      float* gp = pb + (size_t)r0_ * S_TOT + j0 + c8_0 * 8;
      *(float4*)gp = p0;
      *(float4*)(gp + 4) = p1;
      *(u16x8*)&u_s[buf][r0_ * 64 + (c8_0 ^ (r0_ & 7)) * 8] = uu;
    }
    {
      u16x8 uu = ur1;
      if (row_sub[r1_]) uu = (u16x8){0x3F80,0x3F80,0x3F80,0x3F80,0x3F80,0x3F80,0x3F80,0x3F80};
      float iz = row_iz[r1_];
      float4 p0, p1;
      p0.x = __uint_as_float((unsigned)uu[0] << 16) * iz;
      p0.y = __uint_as_float((unsigned)uu[1] << 16) * iz;
      p0.z = __uint_as_float((unsigned)uu[2] << 16) * iz;
      p0.w = __uint_as_float((unsigned)uu[3] << 16) * iz;
      p1.x = __uint_as_float((unsigned)uu[4] << 16) * iz;
      p1.y = __uint_as_float((unsigned)uu[5] << 16) * iz;
      p1.z = __uint_as_float((unsigned)uu[6] << 16) * iz;
      p1.w = __uint_as_float((unsigned)uu[7] << 16) * iz;
      float* gp = pb + (size_t)r1_ * S_TOT + j0 + c8_1 * 8;
      *(float4*)gp = p0;
      *(float4*)(gp + 4) = p1;
      *(u16x8*)&u_s[buf][r1_ * 64 + (c8_1 ^ (r1_ & 7)) * 8] = uu;
    }
    *(u16x8*)&vh_s[buf][(dr_ & 31) * 64 + (c8v ^ (dr_ & 7)) * 8] = vhr;
    *(u16x8*)&vl_s[buf][(dr_ & 31) * 64 + (c8v ^ (dr_ & 7)) * 8] = vlr;

    // prefetch next tile
    if (t < 35) {
      const int j1 = j0 + 64;
      ur0 = *(const u16x8*)(ub + uo0 + j1);
      ur1 = *(const u16x8*)(ub + uo1 + j1);
      vhr = *(const u16x8*)(vhb + vo + j1);
      vlr = *(const u16x8*)(vlb + vo + j1);
    }
    __syncthreads();

    // MFMA phase
    {
      const int row = w * 16 + li;
      const int rs = li & 7;
      s8v a0 = __builtin_bit_cast(s8v, *(const uint4*)&u_s[buf][row * 64 + ((kg)     ^ rs) * 8]);
      s8v a1 = __builtin_bit_cast(s8v, *(const uint4*)&u_s[buf][row * 64 + ((4 + kg) ^ rs) * 8]);
#pragma unroll
      for (int dh = 0; dh < 2; ++dh) {
        const int d = dh * 16 + li;
        const int ds_ = li & 7;
        s8v bh0 = __builtin_bit_cast(s8v, *(const uint4*)&vh_s[buf][d * 64 + ((kg)     ^ ds_) * 8]);
        s8v bl0 = __builtin_bit_cast(s8v, *(const uint4*)&vl_s[buf][d * 64 + ((kg)     ^ ds_) * 8]);
        s8v bh1 = __builtin_bit_cast(s8v, *(const uint4*)&vh_s[buf][d * 64 + ((4 + kg) ^ ds_) * 8]);
        s8v bl1 = __builtin_bit_cast(s8v, *(const uint4*)&vl_s[buf][d * 64 + ((4 + kg) ^ ds_) * 8]);
        acc[dh] = __builtin_amdgcn_mfma_f32_16x16x32_bf16(a0, bh0, acc[dh], 0, 0, 0);
        acc[dh] = __builtin_amdgcn_mfma_f32_16x16x32_bf16(a0, bl0, acc[dh], 0, 0, 0);
        acc[dh] = __builtin_amdgcn_mfma_f32_16x16x32_bf16(a1, bh1, acc[dh], 0, 0, 0);
        acc[dh] = __builtin_amdgcn_mfma_f32_16x16x32_bf16(a1, bl1, acc[dh], 0, 0, 0);
      }
    }
  }

  // epilogue: ctx[b][h*32+d][i] = acc * iz(row);  C: col=li (d), row=kg*4+reg
#pragma unroll
  for (int dh = 0; dh < 2; ++dh) {
#pragma unroll
    for (int reg = 0; reg < 4; ++reg) {
      const int irow = w * 16 + kg * 4 + reg;
      float v = acc[dh][reg] * row_iz[irow];
      ctx[((size_t)(b * C_ + h * 32 + dh * 16 + li)) * S_TOT + i0 + irow] = v;
    }
  }
}

// ---------------------------------------------------------------------------
// Kernel 4a: repack+split conv weights W[co][ci][3][3] -> Wh/Wl[tap][co][ci]
// ---------------------------------------------------------------------------
__global__ __launch_bounds__(256) void k_repackW_split(const float* __restrict__ W,
                                                       ushort_t* __restrict__ Wh,
                                                       ushort_t* __restrict__ Wl) {
  const int co = blockIdx.x, tap = blockIdx.y, ci = threadIdx.x;
  float v = W[((size_t)co * 256 + ci) * 9 + tap];
  ushort_t h = bf16_rn(v);
  float r = __uint_as_float((unsigned)h << 16);
  ushort_t l = bf16_rn(v - r);
  size_t o = ((size_t)tap * 256 + co) * 256 + ci;
  Wh[o] = h;
  Wl[o] = l;
}

// ---------------------------------------------------------------------------
// Kernel 4b: 3x3 SAME conv as split-bf16 MFMA implicit GEMM. (unchanged)
// ---------------------------------------------------------------------------
template<bool DO_SELU>
__global__ __launch_bounds__(256) void k_conv_mfma(
    const float* __restrict__ in,
    const ushort_t* __restrict__ Wh, const ushort_t* __restrict__ Wl,
    const float* __restrict__ bias, float* __restrict__ out) {
  __shared__ __align__(16) ushort_t in_sh[4 * 50 * 40];
  __shared__ __align__(16) ushort_t in_sl[4 * 50 * 40];
  const int tid = threadIdx.x;
  const int w = tid >> 6, lane = tid & 63;
  const int li = lane & 15, kg = lane >> 4;
  const int cg = w & 1, rw = w >> 1;
  const int co0 = blockIdx.x * 32;
  const int y0  = blockIdx.y * 2;
  const int b   = blockIdx.z;

  for (int e = tid; e < 320; e += 256) {
    int sr = e / 80, rem = e % 80;
    int xl = (rem / 40) * 49, ci = rem % 40;
    in_sh[(sr * 50 + xl) * 40 + ci] = 0;
    in_sl[(sr * 50 + xl) * 40 + ci] = 0;
  }

  f32x4 acc[3];
#pragma unroll
  for (int xg = 0; xg < 3; ++xg) acc[xg] = (f32x4){0.f, 0.f, 0.f, 0.f};

  for (int c8 = 0; c8 < 8; ++c8) {
    __syncthreads();
#pragma unroll
    for (int u = 0; u < 6; ++u) {
      int idx = u * 256 + tid;
      int rest = idx / 12;
      int x4 = idx - rest * 12;
      int sr = rest & 3, ci = rest >> 2;
      int gr = y0 - 1 + sr;
      float4 v = make_float4(0.f, 0.f, 0.f, 0.f);
      if (gr >= 0 && gr < 48)
        v = *(const float4*)(in + ((size_t)(b * 256 + c8 * 32 + ci) * 48 + gr) * 48 + x4 * 4);
      ushort_t* bh = &in_sh[(sr * 50 + x4 * 4 + 1) * 40 + ci];
      ushort_t* bl = &in_sl[(sr * 50 + x4 * 4 + 1) * 40 + ci];
      float c[4] = {v.x, v.y, v.z, v.w};
#pragma unroll
      for (int q = 0; q < 4; ++q) {
        ushort_t hq = bf16_rn(c[q]);
        float rq = __uint_as_float((unsigned)hq << 16);
        bh[q * 40] = hq;
        bl[q * 40] = bf16_rn(c[q] - rq);
      }
    }
    __syncthreads();

    s8v ah[9], al[9];
    {
      const ushort_t* wbh = Wh + ((size_t)(co0 + cg * 16 + li)) * 256 + c8 * 32 + kg * 8;
      const ushort_t* wbl = Wl + ((size_t)(co0 + cg * 16 + li)) * 256 + c8 * 32 + kg * 8;
#pragma unroll
      for (int tap = 0; tap < 9; ++tap) {
        ah[tap] = __builtin_bit_cast(s8v, *(const uint4*)(wbh + (size_t)tap * 65536));
        al[tap] = __builtin_bit_cast(s8v, *(const uint4*)(wbl + (size_t)tap * 65536));
      }
    }

#pragma unroll
    for (int ky = 0; ky < 3; ++ky) {
      const int srr = rw + ky;
#pragma unroll
      for (int kx = 0; kx < 3; ++kx) {
        const int tap = ky * 3 + kx;
#pragma unroll
        for (int xg = 0; xg < 3; ++xg) {
          const int xl = xg * 16 + li + kx;
          const ushort_t* bp = &in_sh[(srr * 50 + xl) * 40 + kg * 8];
          const ushort_t* bq = &in_sl[(srr * 50 + xl) * 40 + kg * 8];
          s8v bh = __builtin_bit_cast(s8v, *(const uint4*)bp);
          s8v bl = __builtin_bit_cast(s8v, *(const uint4*)bq);
          acc[xg] = __builtin_amdgcn_mfma_f32_16x16x32_bf16(ah[tap], bh, acc[xg], 0, 0, 0);
          acc[xg] = __builtin_amdgcn_mfma_f32_16x16x32_bf16(ah[tap], bl, acc[xg], 0, 0, 0);
          acc[xg] = __builtin_amdgcn_mfma_f32_16x16x32_bf16(al[tap], bh, acc[xg], 0, 0, 0);
        }
      }
    }
  }

  const int orow = y0 + rw;
#pragma unroll
  for (int reg = 0; reg < 4; ++reg) {
    const int co = co0 + cg * 16 + kg * 4 + reg;
    const float bi = bias[co];
    float* op = out + ((size_t)(b * 256 + co) * 48 + orow) * 48 + li;
#pragma unroll
    for (int xg = 0; xg < 3; ++xg) {
      float y = acc[xg][reg] + bi;
      if (DO_SELU)
        y = 1.0507009873554805f * (y > 0.f ? y : 1.6732632423543772f * expm1f(y));
      op[xg * 16] = y;
    }
  }
}

// ---------------------------------------------------------------------------
extern "C" void kernel_launch(void* const* d_in, const int* in_sizes, int n_in,
                              void* d_out, int out_size, void* d_ws, size_t ws_size,
                              hipStream_t stream) {
  const float* x   = (const float*)d_in[0];
  const float* ref = (const float*)d_in[1];
  const float* qW1 = (const float*)d_in[2];
  const float* qb1 = (const float*)d_in[3];
  const float* qW2 = (const float*)d_in[4];
  const float* qb2 = (const float*)d_in[5];
  const float* kW1 = (const float*)d_in[6];
  const float* kb1 = (const float*)d_in[7];
  const float* kW2 = (const float*)d_in[8];
  const float* kb2 = (const float*)d_in[9];
  const float* vW1 = (const float*)d_in[10];
  const float* vb1 = (const float*)d_in[11];
  const float* vW2 = (const float*)d_in[12];
  const float* vb2 = (const float*)d_in[13];
  const float* c1W = (const float*)d_in[14];
  const float* c1b = (const float*)d_in[15];
  const float* c2W = (const float*)d_in[16];
  const float* c2b = (const float*)d_in[17];

  float* out = (float*)d_out;
  float* probs = out + (size_t)B_ * C_ * S_TOT;       // [B][H][S][S]
  float* ws = (float*)d_ws;
  const size_t BSC = (size_t)B_ * S_TOT * C_;         // 1,179,648
  const size_t STATS = (size_t)4 * B_ * HEADS_ * S_TOT;
  const size_t WTSZ = (size_t)256 * 9 * 256;

  float* Qb  = ws;
  float* Kb  = Qb + BSC;
  float* Vb  = Kb + BSC;
  float* Ht  = Vb + BSC;
  float* stz = Ht + BSC;
  float* ctx = stz + STATS;
  float* tmp1 = ctx + BSC;
  float* Wt1 = tmp1 + BSC;
  float* Wt2 = Wt1 + WTSZ;
  float* endf = Wt2 + WTSZ;

  // bf16 split planes: Q planes in Ht (free after MLPs), K planes in Qb.
  ushort_t* QhP = (ushort_t*)Ht;
  ushort_t* QlP = QhP + BSC;
  ushort_t* KhP = (ushort_t*)Qb;
  ushort_t* KlP = KhP + BSC;

  // conv weight split planes in the Wt regions (exact fit)
  ushort_t* Wh1 = (ushort_t*)Wt1;
  ushort_t* Wl1 = Wh1 + WTSZ;
  ushort_t* Wh2 = (ushort_t*)Wt2;
  ushort_t* Wl2 = Wh2 + WTSZ;

  // new buffers after the float region: V^T planes + U (bf16 unnormalized probs)
  ushort_t* VhT = (ushort_t*)endf;
  ushort_t* VlT = VhT + BSC;
  ushort_t* Ubuf = VlT + BSC;   // 2*8*2304*2304 ushorts = ~170 MB

  dim3 blk(256);
  k_repackW_split<<<dim3(256, 9), blk, 0, stream>>>(c1W, Wh1, Wl1);
  k_repackW_split<<<dim3(256, 9), blk, 0, stream>>>(c2W, Wh2, Wl2);

  dim3 gmlp(72, B_);
  k_mlp<0><<<gmlp, blk, 0, stream>>>(x,   qW1, qb1, Ht);
  k_mlp<1><<<gmlp, blk, 0, stream>>>(Ht,  qW2, qb2, Qb);
  k_mlp<0><<<gmlp, blk, 0, stream>>>(ref, kW1, kb1, Ht);
  k_mlp<1><<<gmlp, blk, 0, stream>>>(Ht,  kW2, kb2, Kb);
  k_mlp<0><<<gmlp, blk, 0, stream>>>(ref, vW1, vb1, Ht);
  k_mlp<1><<<gmlp, blk, 0, stream>>>(Ht,  vW2, vb2, Vb);

  const int nsplit = (int)(BSC / 4 / 256);            // 1152 blocks
  k_split<<<dim3(nsplit), blk, 0, stream>>>(Qb, QhP, QlP);   // Q -> Ht space
  k_split<<<dim3(nsplit), blk, 0, stream>>>(Kb, KhP, KlP);   // K -> Qb space
  k_splitT<<<dim3(36, 4, B_), blk, 0, stream>>>(Vb, VhT, VlT);

  k_scores_mfma<<<dim3(36, 4, B_), blk, 0, stream>>>(QhP, QlP, KhP, KlP,
                                                     Ubuf, stz);

  k_pv4<<<dim3(36, 8, B_), blk, 0, stream>>>(Ubuf, stz, VhT, VlT, probs, ctx);

  k_conv_mfma<true ><<<dim3(8, 24, B_), blk, 0, stream>>>(ctx,  Wh1, Wl1, c1b, tmp1);
  k_conv_mfma<false><<<dim3(8, 24, B_), blk, 0, stream>>>(tmp1, Wh2, Wl2, c2b, out);
}

// Round 9
// 605.731 us; speedup vs baseline: 1.8355x; 1.5032x over previous
//
#include <hip/hip_runtime.h>
#include <hip/hip_bf16.h>

typedef unsigned short ushort_t;
typedef short s8v __attribute__((ext_vector_type(8)));      // 8 bf16 bit-patterns
typedef ushort_t u16x8 __attribute__((ext_vector_type(8))); // 8 ushorts (16B)
typedef float f32x4 __attribute__((ext_vector_type(4)));

// Problem constants
constexpr int B_ = 2;
constexpr int C_ = 256;
constexpr int S_TOT = 48 * 48;   // 2304
constexpr int HEADS_ = 8;
#define INV_SQRT_DH 0.17677669529663688f

__device__ __forceinline__ ushort_t bf16_rn(float x) {
  unsigned u = __float_as_uint(x);
  return (ushort_t)((u + 0x7fffu + ((u >> 16) & 1u)) >> 16);
}

// ---------------------------------------------------------------------------
// Kernel 1 (fused x3): first MLP layers. in [b][C][S] -> H [b][s][C], relu.
// grid (72, B, 3).
// ---------------------------------------------------------------------------
__global__ __launch_bounds__(256) void k_mlp1f(
    const float* __restrict__ x, const float* __restrict__ ref,
    const float* __restrict__ qW1, const float* __restrict__ qb1,
    const float* __restrict__ kW1, const float* __restrict__ kb1,
    const float* __restrict__ vW1, const float* __restrict__ vb1,
    float* __restrict__ Hq, float* __restrict__ Hk, float* __restrict__ Hv) {
  __shared__ __align__(16) float in_s[32][260];
  const int tid = threadIdx.x;
  const int s0 = blockIdx.x * 32;
  const int b  = blockIdx.y;
  const int z  = blockIdx.z;
  const float* in = (z == 0) ? x : ref;
  const float* Wm = (z == 0) ? qW1 : (z == 1) ? kW1 : vW1;
  const float* bias = (z == 0) ? qb1 : (z == 1) ? kb1 : vb1;
  float* out = (z == 0) ? Hq : (z == 1) ? Hk : Hv;

  for (int idx = tid; idx < 32 * 256; idx += 256) {
    int ci = idx >> 5, r = idx & 31;
    in_s[r][ci] = in[((size_t)b * C_ + ci) * S_TOT + s0 + r];
  }
  __syncthreads();

  const int co = tid;
  float acc[32];
#pragma unroll
  for (int r = 0; r < 32; ++r) acc[r] = 0.f;
  for (int c4 = 0; c4 < 64; ++c4) {
    const float w0 = Wm[(c4 * 4 + 0) * C_ + co];
    const float w1 = Wm[(c4 * 4 + 1) * C_ + co];
    const float w2 = Wm[(c4 * 4 + 2) * C_ + co];
    const float w3 = Wm[(c4 * 4 + 3) * C_ + co];
#pragma unroll
    for (int r = 0; r < 32; ++r) {
      float4 a = *(const float4*)&in_s[r][c4 * 4];
      acc[r] = fmaf(a.x, w0, fmaf(a.y, w1, fmaf(a.z, w2, fmaf(a.w, w3, acc[r]))));
    }
  }
  const float bi = bias[co];
#pragma unroll 4
  for (int r = 0; r < 32; ++r)
    out[((size_t)b * S_TOT + s0 + r) * C_ + co] = fmaxf(acc[r] + bi, 0.f);
}

// ---------------------------------------------------------------------------
// Kernel 2 (fused x3): second MLP layers -> bf16 hi/lo planes directly.
// z=0: Hq->Qh/Ql [b][s][C]; z=1: Hk->Kh/Kl; z=2: Hv->VhT/VlT [b][C][s].
// ---------------------------------------------------------------------------
__global__ __launch_bounds__(256) void k_mlp2f(
    const float* __restrict__ Hq, const float* __restrict__ Hk,
    const float* __restrict__ Hv,
    const float* __restrict__ qW2, const float* __restrict__ qb2,
    const float* __restrict__ kW2, const float* __restrict__ kb2,
    const float* __restrict__ vW2, const float* __restrict__ vb2,
    ushort_t* __restrict__ Qh, ushort_t* __restrict__ Ql,
    ushort_t* __restrict__ Kh, ushort_t* __restrict__ Kl,
    ushort_t* __restrict__ VhT, ushort_t* __restrict__ VlT) {
  __shared__ __align__(16) float in_s[32][260];
  const int tid = threadIdx.x;
  const int s0 = blockIdx.x * 32;
  const int b  = blockIdx.y;
  const int z  = blockIdx.z;
  const float* in = (z == 0) ? Hq : (z == 1) ? Hk : Hv;
  const float* Wm = (z == 0) ? qW2 : (z == 1) ? kW2 : vW2;
  const float* bias = (z == 0) ? qb2 : (z == 1) ? kb2 : vb2;

  for (int idx = tid; idx < 32 * 256; idx += 256) {
    int r = idx >> 8, ci = idx & 255;
    in_s[r][ci] = in[((size_t)b * S_TOT + s0 + r) * C_ + ci];
  }
  __syncthreads();

  const int co = tid;
  float acc[32];
#pragma unroll
  for (int r = 0; r < 32; ++r) acc[r] = 0.f;
  for (int c4 = 0; c4 < 64; ++c4) {
    const float w0 = Wm[(c4 * 4 + 0) * C_ + co];
    const float w1 = Wm[(c4 * 4 + 1) * C_ + co];
    const float w2 = Wm[(c4 * 4 + 2) * C_ + co];
    const float w3 = Wm[(c4 * 4 + 3) * C_ + co];
#pragma unroll
    for (int r = 0; r < 32; ++r) {
      float4 a = *(const float4*)&in_s[r][c4 * 4];
      acc[r] = fmaf(a.x, w0, fmaf(a.y, w1, fmaf(a.z, w2, fmaf(a.w, w3, acc[r]))));
    }
  }
  const float bi = bias[co];

  if (z < 2) {
    ushort_t* Ph = (z == 0) ? Qh : Kh;
    ushort_t* Pl = (z == 0) ? Ql : Kl;
#pragma unroll 4
    for (int r = 0; r < 32; ++r) {
      float y = fmaxf(acc[r] + bi, 0.f);
      ushort_t h = bf16_rn(y);
      float hf = __uint_as_float((unsigned)h << 16);
      ushort_t l = bf16_rn(y - hf);
      size_t o = ((size_t)b * S_TOT + s0 + r) * C_ + co;
      Ph[o] = h;
      Pl[o] = l;
    }
  } else {
    ushort_t hs[32], ls[32];
#pragma unroll
    for (int r = 0; r < 32; ++r) {
      float y = fmaxf(acc[r] + bi, 0.f);
      ushort_t h = bf16_rn(y);
      float hf = __uint_as_float((unsigned)h << 16);
      hs[r] = h;
      ls[r] = bf16_rn(y - hf);
    }
    size_t base = ((size_t)b * C_ + co) * S_TOT + s0;
#pragma unroll
    for (int k = 0; k < 4; ++k) {
      u16x8 hv, lv;
#pragma unroll
      for (int q = 0; q < 8; ++q) { hv[q] = hs[k * 8 + q]; lv[q] = ls[k * 8 + q]; }
      *(u16x8*)(VhT + base + k * 8) = hv;
      *(u16x8*)(VlT + base + k * 8) = lv;
    }
  }
}

// ---------------------------------------------------------------------------
// Kernel 3 (MFMA): scores + top-1-over-heads mask -> U bf16 + Z partials.
// (verified structure, unchanged)
// ---------------------------------------------------------------------------
__global__ __launch_bounds__(256) void k_scores_mfma(
    const ushort_t* __restrict__ Qh, const ushort_t* __restrict__ Ql,
    const ushort_t* __restrict__ Kh, const ushort_t* __restrict__ Kl,
    ushort_t* __restrict__ U, float* __restrict__ st_z) {
  __shared__ __align__(16) uint4 kh_s[64 * 32];
  __shared__ __align__(16) uint4 kl_s[64 * 32];
  const int tid = threadIdx.x;
  const int w = tid >> 6, lane = tid & 63;
  const int li = lane & 15, kg = lane >> 4;
  const int i0 = blockIdx.x * 64;
  const int js = blockIdx.y;
  const int b  = blockIdx.z;
  const int jbase = js * 576;

  s8v ahi[8], alo[8];
  {
    const ushort_t* qh = Qh + ((size_t)b * S_TOT + i0 + w * 16 + li) * C_ + kg * 8;
    const ushort_t* ql = Ql + ((size_t)b * S_TOT + i0 + w * 16 + li) * C_ + kg * 8;
#pragma unroll
    for (int h = 0; h < 8; ++h) {
      ahi[h] = __builtin_bit_cast(s8v, *(const uint4*)(qh + h * 32));
      alo[h] = __builtin_bit_cast(s8v, *(const uint4*)(ql + h * 32));
    }
  }

  float zacc[4][8];
#pragma unroll
  for (int r = 0; r < 4; ++r)
#pragma unroll
    for (int h = 0; h < 8; ++h) zacc[r][h] = 0.f;

  for (int jt = 0; jt < 9; ++jt) {
    const int j0 = jbase + jt * 64;
    __syncthreads();
    for (int e = tid; e < 2048; e += 256) {
      int r = e >> 5, c = e & 31;
      size_t goff = ((size_t)b * S_TOT + j0 + r) * C_ + c * 8;
      int cs = c ^ (r & 7);
      kh_s[r * 32 + cs] = *(const uint4*)(Kh + goff);
      kl_s[r * 32 + cs] = *(const uint4*)(Kl + goff);
    }
    __syncthreads();

#pragma unroll
    for (int jsub = 0; jsub < 4; ++jsub) {
      const int rj = jsub * 16 + li;
      f32x4 sc[8];
#pragma unroll
      for (int h = 0; h < 8; ++h) {
        const int cs = (h * 4 + kg) ^ (rj & 7);
        s8v bhi = __builtin_bit_cast(s8v, kh_s[rj * 32 + cs]);
        s8v blo = __builtin_bit_cast(s8v, kl_s[rj * 32 + cs]);
        f32x4 acc = {0.f, 0.f, 0.f, 0.f};
        acc = __builtin_amdgcn_mfma_f32_16x16x32_bf16(ahi[h], bhi, acc, 0, 0, 0);
        acc = __builtin_amdgcn_mfma_f32_16x16x32_bf16(ahi[h], blo, acc, 0, 0, 0);
        acc = __builtin_amdgcn_mfma_f32_16x16x32_bf16(alo[h], bhi, acc, 0, 0, 0);
        sc[h] = acc;
      }
      const int jcol = j0 + jsub * 16 + li;
#pragma unroll
      for (int reg = 0; reg < 4; ++reg) {
        float s8_[8];
        float thr = -1e30f;
#pragma unroll
        for (int h = 0; h < 8; ++h) {
          s8_[h] = sc[h][reg] * INV_SQRT_DH;
          thr = fmaxf(thr, s8_[h]);
        }
        const int i = i0 + w * 16 + kg * 4 + reg;
#pragma unroll
        for (int h = 0; h < 8; ++h) {
          float mv = s8_[h] < thr ? -1e18f : s8_[h];
          float uf = __expf(mv);            // 0 exactly when masked
          ushort_t ub = bf16_rn(uf);
          U[((size_t)((b * 8 + h) * S_TOT + i)) * S_TOT + jcol] = ub;
          zacc[reg][h] += __uint_as_float((unsigned)ub << 16);
        }
      }
    }
  }

#pragma unroll
  for (int reg = 0; reg < 4; ++reg) {
#pragma unroll
    for (int h = 0; h < 8; ++h) {
      float z = zacc[reg][h];
      z += __shfl_xor(z, 1);
      z += __shfl_xor(z, 2);
      z += __shfl_xor(z, 4);
      z += __shfl_xor(z, 8);
      if (li == 0) {
        const int i = i0 + w * 16 + kg * 4 + reg;
        size_t sidx = ((size_t)(js * B_ + b) * HEADS_ + h) * S_TOT + i;
        st_z[sidx] = z;
      }
    }
  }
}

// ---------------------------------------------------------------------------
// Kernel 4: probs = U/Z + ctx via bf16 MFMA; ctx -> transposed bf16 planes.
// ---------------------------------------------------------------------------
__global__ __launch_bounds__(256) void k_pv4(const ushort_t* __restrict__ U,
                                             const float* __restrict__ st_z,
                                             const ushort_t* __restrict__ VhT,
                                             const ushort_t* __restrict__ VlT,
                                             float* __restrict__ probs,
                                             ushort_t* __restrict__ ctxTh,
                                             ushort_t* __restrict__ ctxTl) {
  __shared__ __align__(16) ushort_t u_s[2][64 * 64];
  __shared__ __align__(16) ushort_t vh_s[2][32 * 64];
  __shared__ __align__(16) ushort_t vl_s[2][32 * 64];
  __shared__ float row_iz[64];
  __shared__ int   row_sub[64];
  const int tid = threadIdx.x;
  const int w = tid >> 6, lane = tid & 63;
  const int li = lane & 15, kg = lane >> 4;
  const int i0 = blockIdx.x * 64;
  const int h  = blockIdx.y;
  const int b  = blockIdx.z;

  if (tid < 64) {
    const int i = i0 + tid;
    float Z = 0.f;
#pragma unroll
    for (int js = 0; js < 4; ++js)
      Z += st_z[((size_t)(js * B_ + b) * HEADS_ + h) * S_TOT + i];
    if (Z == 0.f) { row_iz[tid] = 1.0f / (float)S_TOT; row_sub[tid] = 1; }
    else          { row_iz[tid] = 1.0f / Z;            row_sub[tid] = 0; }
  }

  const ushort_t* ub = U + ((size_t)((b * 8 + h) * S_TOT + i0)) * S_TOT;
  float* pb = probs + ((size_t)((b * 8 + h) * S_TOT + i0)) * S_TOT;
  const ushort_t* vhb = VhT + ((size_t)(b * C_ + h * 32)) * S_TOT;
  const ushort_t* vlb = VlT + ((size_t)(b * C_ + h * 32)) * S_TOT;

  const int r0_  = tid >> 3,         c8_0 = tid & 7;
  const int r1_  = (tid + 256) >> 3, c8_1 = tid & 7;
  const int dr_  = tid >> 3, c8v = tid & 7;
  const size_t uo0 = (size_t)r0_ * S_TOT + c8_0 * 8;
  const size_t uo1 = (size_t)r1_ * S_TOT + c8_1 * 8;
  const size_t vo  = (size_t)(dr_ & 31) * S_TOT + c8v * 8;

  f32x4 acc[2];
  acc[0] = (f32x4){0.f, 0.f, 0.f, 0.f};
  acc[1] = (f32x4){0.f, 0.f, 0.f, 0.f};

  u16x8 ur0 = *(const u16x8*)(ub + uo0);
  u16x8 ur1 = *(const u16x8*)(ub + uo1);
  u16x8 vhr = *(const u16x8*)(vhb + vo);
  u16x8 vlr = *(const u16x8*)(vlb + vo);
  __syncthreads();

  for (int t = 0; t < 36; ++t) {
    const int j0 = t * 64;
    const int buf = t & 1;

    {
      u16x8 uu = ur0;
      if (row_sub[r0_]) uu = (u16x8){0x3F80,0x3F80,0x3F80,0x3F80,0x3F80,0x3F80,0x3F80,0x3F80};
      float iz = row_iz[r0_];
      float4 p0, p1;
      p0.x = __uint_as_float((unsigned)uu[0] << 16) * iz;
      p0.y = __uint_as_float((unsigned)uu[1] << 16) * iz;
      p0.z = __uint_as_float((unsigned)uu[2] << 16) * iz;
      p0.w = __uint_as_float((unsigned)uu[3] << 16) * iz;
      p1.x = __uint_as_float((unsigned)uu[4] << 16) * iz;
      p1.y = __uint_as_float((unsigned)uu[5] << 16) * iz;
      p1.z = __uint_as_float((unsigned)uu[6] << 16) * iz;
      p1.w = __uint_as_float((unsigned)uu[7] << 16) * iz;
      float* gp = pb + (size_t)r0_ * S_TOT + j0 + c8_0 * 8;
      *(float4*)gp = p0;
      *(float4*)(gp + 4) = p1;
      *(u16x8*)&u_s[buf][r0_ * 64 + (c8_0 ^ (r0_ & 7)) * 8] = uu;
    }
    {
      u16x8 uu = ur1;
      if (row_sub[r1_]) uu = (u16x8){0x3F80,0x3F80,0x3F80,0x3F80,0x3F80,0x3F80,0x3F80,0x3F80};
      float iz = row_iz[r1_];
      float4 p0, p1;
      p0.x = __uint_as_float((unsigned)uu[0] << 16) * iz;
      p0.y = __uint_as_float((unsigned)uu[1] << 16) * iz;
      p0.z = __uint_as_float((unsigned)uu[2] << 16) * iz;
      p0.w = __uint_as_float((unsigned)uu[3] << 16) * iz;
      p1.x = __uint_as_float((unsigned)uu[4] << 16) * iz;
      p1.y = __uint_as_float((unsigned)uu[5] << 16) * iz;
      p1.z = __uint_as_float((unsigned)uu[6] << 16) * iz;
      p1.w = __uint_as_float((unsigned)uu[7] << 16) * iz;
      float* gp = pb + (size_t)r1_ * S_TOT + j0 + c8_1 * 8;
      *(float4*)gp = p0;
      *(float4*)(gp + 4) = p1;
      *(u16x8*)&u_s[buf][r1_ * 64 + (c8_1 ^ (r1_ & 7)) * 8] = uu;
    }
    *(u16x8*)&vh_s[buf][(dr_ & 31) * 64 + (c8v ^ (dr_ & 7)) * 8] = vhr;
    *(u16x8*)&vl_s[buf][(dr_ & 31) * 64 + (c8v ^ (dr_ & 7)) * 8] = vlr;

    if (t < 35) {
      const int j1 = j0 + 64;
      ur0 = *(const u16x8*)(ub + uo0 + j1);
      ur1 = *(const u16x8*)(ub + uo1 + j1);
      vhr = *(const u16x8*)(vhb + vo + j1);
      vlr = *(const u16x8*)(vlb + vo + j1);
    }
    __syncthreads();

    {
      const int row = w * 16 + li;
      const int rs = li & 7;
      s8v a0 = __builtin_bit_cast(s8v, *(const uint4*)&u_s[buf][row * 64 + ((kg)     ^ rs) * 8]);
      s8v a1 = __builtin_bit_cast(s8v, *(const uint4*)&u_s[buf][row * 64 + ((4 + kg) ^ rs) * 8]);
#pragma unroll
      for (int dh = 0; dh < 2; ++dh) {
        const int d = dh * 16 + li;
        const int ds_ = li & 7;
        s8v bh0 = __builtin_bit_cast(s8v, *(const uint4*)&vh_s[buf][d * 64 + ((kg)     ^ ds_) * 8]);
        s8v bl0 = __builtin_bit_cast(s8v, *(const uint4*)&vl_s[buf][d * 64 + ((kg)     ^ ds_) * 8]);
        s8v bh1 = __builtin_bit_cast(s8v, *(const uint4*)&vh_s[buf][d * 64 + ((4 + kg) ^ ds_) * 8]);
        s8v bl1 = __builtin_bit_cast(s8v, *(const uint4*)&vl_s[buf][d * 64 + ((4 + kg) ^ ds_) * 8]);
        acc[dh] = __builtin_amdgcn_mfma_f32_16x16x32_bf16(a0, bh0, acc[dh], 0, 0, 0);
        acc[dh] = __builtin_amdgcn_mfma_f32_16x16x32_bf16(a0, bl0, acc[dh], 0, 0, 0);
        acc[dh] = __builtin_amdgcn_mfma_f32_16x16x32_bf16(a1, bh1, acc[dh], 0, 0, 0);
        acc[dh] = __builtin_amdgcn_mfma_f32_16x16x32_bf16(a1, bl1, acc[dh], 0, 0, 0);
      }
    }
  }

#pragma unroll
  for (int dh = 0; dh < 2; ++dh) {
#pragma unroll
    for (int reg = 0; reg < 4; ++reg) {
      const int irow = w * 16 + kg * 4 + reg;
      float v = acc[dh][reg] * row_iz[irow];
      ushort_t hh = bf16_rn(v);
      float hf = __uint_as_float((unsigned)hh << 16);
      ushort_t ll = bf16_rn(v - hf);
      size_t o = ((size_t)b * S_TOT + i0 + irow) * C_ + h * 32 + dh * 16 + li;
      ctxTh[o] = hh;
      ctxTl[o] = ll;
    }
  }
}

// ---------------------------------------------------------------------------
// Kernel 5a: repack+split conv weights -> Wh/Wl[tap][co][ci]
// ---------------------------------------------------------------------------
__global__ __launch_bounds__(256) void k_repackW_split(const float* __restrict__ W,
                                                       ushort_t* __restrict__ Wh,
                                                       ushort_t* __restrict__ Wl) {
  const int co = blockIdx.x, tap = blockIdx.y, ci = threadIdx.x;
  float v = W[((size_t)co * 256 + ci) * 9 + tap];
  ushort_t h = bf16_rn(v);
  float r = __uint_as_float((unsigned)h << 16);
  ushort_t l = bf16_rn(v - r);
  size_t o = ((size_t)tap * 256 + co) * 256 + ci;
  Wh[o] = h;
  Wl[o] = l;
}

// ---------------------------------------------------------------------------
// Kernel 5b: conv MFMA v2 — input pre-split/transposed bf16 [b][s][c].
// grid (8 co-tiles, 24 y-pairs, 2 b), block 256. Template CH = ci half.
// Staging = pure u16x8 copies; A-frags per-tap; partial f32 out.
// ---------------------------------------------------------------------------
template<int CH>
__global__ __launch_bounds__(256) void k_conv_mfma2(
    const ushort_t* __restrict__ inTh, const ushort_t* __restrict__ inTl,
    const ushort_t* __restrict__ Wh, const ushort_t* __restrict__ Wl,
    float* __restrict__ part) {
  __shared__ __align__(16) ushort_t in_sh[4 * 50 * 40];
  __shared__ __align__(16) ushort_t in_sl[4 * 50 * 40];
  const int tid = threadIdx.x;
  const int w = tid >> 6, lane = tid & 63;
  const int li = lane & 15, kg = lane >> 4;
  const int cg = w & 1, rw = w >> 1;
  const int co0 = blockIdx.x * 32;
  const int y0  = blockIdx.y * 2;
  const int b   = blockIdx.z;

  for (int e = tid; e < 320; e += 256) {
    int sr = e / 80, rem = e % 80;
    int xl = (rem / 40) * 49, ci = rem % 40;
    in_sh[(sr * 50 + xl) * 40 + ci] = 0;
    in_sl[(sr * 50 + xl) * 40 + ci] = 0;
  }

  f32x4 acc[3];
#pragma unroll
  for (int xg = 0; xg < 3; ++xg) acc[xg] = (f32x4){0.f, 0.f, 0.f, 0.f};

  for (int c8 = 0; c8 < 4; ++c8) {
    const int ci0 = CH * 128 + c8 * 32;
    __syncthreads();
#pragma unroll
    for (int t = 0; t < 3; ++t) {
      int id = t * 256 + tid;
      int cig = id & 3;
      int xx  = (id >> 2) % 48;
      int sr  = id / 192;
      int gr  = y0 - 1 + sr;
      u16x8 vh = {0,0,0,0,0,0,0,0}, vl = {0,0,0,0,0,0,0,0};
      if (gr >= 0 && gr < 48) {
        size_t go = ((size_t)b * S_TOT + gr * 48 + xx) * C_ + ci0 + cig * 8;
        vh = *(const u16x8*)(inTh + go);
        vl = *(const u16x8*)(inTl + go);
      }
      int lo = (sr * 50 + xx + 1) * 40 + cig * 8;
      *(u16x8*)&in_sh[lo] = vh;
      *(u16x8*)&in_sl[lo] = vl;
    }
    __syncthreads();

#pragma unroll
    for (int ky = 0; ky < 3; ++ky) {
      const int srr = rw + ky;
#pragma unroll
      for (int kx = 0; kx < 3; ++kx) {
        const int tap = ky * 3 + kx;
        size_t wo = ((size_t)tap * 256 + co0 + cg * 16 + li) * 256 + ci0 + kg * 8;
        s8v ah = __builtin_bit_cast(s8v, *(const uint4*)(Wh + wo));
        s8v al = __builtin_bit_cast(s8v, *(const uint4*)(Wl + wo));
#pragma unroll
        for (int xg = 0; xg < 3; ++xg) {
          const int xl = xg * 16 + li + kx;
          s8v bh = __builtin_bit_cast(s8v, *(const uint4*)&in_sh[(srr * 50 + xl) * 40 + kg * 8]);
          s8v bl = __builtin_bit_cast(s8v, *(const uint4*)&in_sl[(srr * 50 + xl) * 40 + kg * 8]);
          acc[xg] = __builtin_amdgcn_mfma_f32_16x16x32_bf16(ah, bh, acc[xg], 0, 0, 0);
          acc[xg] = __builtin_amdgcn_mfma_f32_16x16x32_bf16(ah, bl, acc[xg], 0, 0, 0);
          acc[xg] = __builtin_amdgcn_mfma_f32_16x16x32_bf16(al, bh, acc[xg], 0, 0, 0);
        }
      }
    }
  }

  const int orow = y0 + rw;
#pragma unroll
  for (int reg = 0; reg < 4; ++reg) {
    const int co = co0 + cg * 16 + kg * 4 + reg;
    float* op = part + ((size_t)(b * 256 + co) * 48 + orow) * 48 + li;
#pragma unroll
    for (int xg = 0; xg < 3; ++xg) op[xg * 16] = acc[xg][reg];
  }
}

// ---------------------------------------------------------------------------
// Kernel 5c: y = selu(Cp0+Cp1+bias), transpose+split -> t1T hi/lo [b][s][c].
// grid (36 s-tiles, 4 co-tiles, B).
// ---------------------------------------------------------------------------
__global__ __launch_bounds__(256) void k_act_t(const float* __restrict__ p0,
                                               const float* __restrict__ p1,
                                               const float* __restrict__ bias,
                                               ushort_t* __restrict__ outTh,
                                               ushort_t* __restrict__ outTl) {
  __shared__ __align__(16) float t_s[64][65];
  const int tid = threadIdx.x;
  const int s0 = blockIdx.x * 64;
  const int co0 = blockIdx.y * 64;
  const int b  = blockIdx.z;

#pragma unroll
  for (int k = 0; k < 16; ++k) {
    int idx = tid + k * 256;
    int r = idx >> 6, c = idx & 63;
    size_t a = ((size_t)(b * 256 + co0 + r)) * S_TOT + s0 + c;
    float v = p0[a] + p1[a] + bias[co0 + r];
    v = 1.0507009873554805f * (v > 0.f ? v : 1.6732632423543772f * expm1f(v));
    t_s[r][c] = v;
  }
  __syncthreads();
#pragma unroll
  for (int k = 0; k < 16; ++k) {
    int idx = tid + k * 256;
    int p = idx >> 6, c = idx & 63;
    float v = t_s[c][p];
    ushort_t h = bf16_rn(v);
    float hf = __uint_as_float((unsigned)h << 16);
    ushort_t l = bf16_rn(v - hf);
    size_t o = ((size_t)b * S_TOT + s0 + p) * C_ + co0 + c;
    outTh[o] = h;
    outTl[o] = l;
  }
}

// ---------------------------------------------------------------------------
// Kernel 5d: out = Cp0 + Cp1 + bias (f32, no act)
// ---------------------------------------------------------------------------
__global__ __launch_bounds__(256) void k_act2(const float* __restrict__ p0,
                                              const float* __restrict__ p1,
                                              const float* __restrict__ bias,
                                              float* __restrict__ out) {
  size_t i4 = ((size_t)blockIdx.x * 256 + threadIdx.x) * 4;
  float4 a = *(const float4*)(p0 + i4);
  float4 b = *(const float4*)(p1 + i4);
  int co = (int)((i4 / (size_t)S_TOT) & 255);
  float bi = bias[co];
  float4 o;
  o.x = a.x + b.x + bi; o.y = a.y + b.y + bi;
  o.z = a.z + b.z + bi; o.w = a.w + b.w + bi;
  *(float4*)(out + i4) = o;
}

// ---------------------------------------------------------------------------
extern "C" void kernel_launch(void* const* d_in, const int* in_sizes, int n_in,
                              void* d_out, int out_size, void* d_ws, size_t ws_size,
                              hipStream_t stream) {
  const float* x   = (const float*)d_in[0];
  const float* ref = (const float*)d_in[1];
  const float* qW1 = (const float*)d_in[2];
  const float* qb1 = (const float*)d_in[3];
  const float* qW2 = (const float*)d_in[4];
  const float* qb2 = (const float*)d_in[5];
  const float* kW1 = (const float*)d_in[6];
  const float* kb1 = (const float*)d_in[7];
  const float* kW2 = (const float*)d_in[8];
  const float* kb2 = (const float*)d_in[9];
  const float* vW1 = (const float*)d_in[10];
  const float* vb1 = (const float*)d_in[11];
  const float* vW2 = (const float*)d_in[12];
  const float* vb2 = (const float*)d_in[13];
  const float* c1W = (const float*)d_in[14];
  const float* c1b = (const float*)d_in[15];
  const float* c2W = (const float*)d_in[16];
  const float* c2b = (const float*)d_in[17];

  float* out = (float*)d_out;
  float* probs = out + (size_t)B_ * C_ * S_TOT;       // [B][H][S][S]
  float* ws = (float*)d_ws;
  const size_t BSC = (size_t)B_ * S_TOT * C_;         // 1,179,648
  const size_t STATS = (size_t)4 * B_ * HEADS_ * S_TOT;
  const size_t WTSZ = (size_t)256 * 9 * 256;

  float* Hq  = ws;
  float* Hk  = Hq + BSC;
  float* Hv  = Hk + BSC;
  float* stz = Hv + BSC;
  float* Cp0 = stz + STATS;
  float* Cp1 = Cp0 + BSC;
  float* endf = Cp1 + BSC;

  ushort_t* Qh  = (ushort_t*)endf;
  ushort_t* Ql  = Qh + BSC;
  ushort_t* Kh  = Ql + BSC;
  ushort_t* Kl  = Kh + BSC;
  ushort_t* VhT = Kl + BSC;
  ushort_t* VlT = VhT + BSC;
  ushort_t* cTh = VlT + BSC;
  ushort_t* cTl = cTh + BSC;
  ushort_t* t1h = cTl + BSC;
  ushort_t* t1l = t1h + BSC;
  ushort_t* Wh1 = t1l + BSC;
  ushort_t* Wl1 = Wh1 + WTSZ;
  ushort_t* Wh2 = Wl1 + WTSZ;
  ushort_t* Wl2 = Wh2 + WTSZ;
  ushort_t* Ubuf = Wl2 + WTSZ;   // ~170 MB

  dim3 blk(256);
  k_repackW_split<<<dim3(256, 9), blk, 0, stream>>>(c1W, Wh1, Wl1);
  k_repackW_split<<<dim3(256, 9), blk, 0, stream>>>(c2W, Wh2, Wl2);

  k_mlp1f<<<dim3(72, B_, 3), blk, 0, stream>>>(x, ref, qW1, qb1, kW1, kb1,
                                               vW1, vb1, Hq, Hk, Hv);
  k_mlp2f<<<dim3(72, B_, 3), blk, 0, stream>>>(Hq, Hk, Hv, qW2, qb2, kW2, kb2,
                                               vW2, vb2, Qh, Ql, Kh, Kl, VhT, VlT);

  k_scores_mfma<<<dim3(36, 4, B_), blk, 0, stream>>>(Qh, Ql, Kh, Kl, Ubuf, stz);

  k_pv4<<<dim3(36, 8, B_), blk, 0, stream>>>(Ubuf, stz, VhT, VlT, probs, cTh, cTl);

  dim3 gconv(8, 24, B_);
  k_conv_mfma2<0><<<gconv, blk, 0, stream>>>(cTh, cTl, Wh1, Wl1, Cp0);
  k_conv_mfma2<1><<<gconv, blk, 0, stream>>>(cTh, cTl, Wh1, Wl1, Cp1);
  k_act_t<<<dim3(36, 4, B_), blk, 0, stream>>>(Cp0, Cp1, c1b, t1h, t1l);
  k_conv_mfma2<0><<<gconv, blk, 0, stream>>>(t1h, t1l, Wh2, Wl2, Cp0);
  k_conv_mfma2<1><<<gconv, blk, 0, stream>>>(t1h, t1l, Wh2, Wl2, Cp1);
  k_act2<<<dim3((int)(BSC / 1024)), blk, 0, stream>>>(Cp0, Cp1, c2b, out);
}

// Round 10
// 489.207 us; speedup vs baseline: 2.2727x; 1.2382x over previous
//
#include <hip/hip_runtime.h>
#include <hip/hip_bf16.h>

typedef unsigned short ushort_t;
typedef short s8v __attribute__((ext_vector_type(8)));      // 8 bf16 bit-patterns
typedef ushort_t u16x8 __attribute__((ext_vector_type(8))); // 8 ushorts (16B)
typedef float f32x4 __attribute__((ext_vector_type(4)));

// Problem constants
constexpr int B_ = 2;
constexpr int C_ = 256;
constexpr int S_TOT = 48 * 48;   // 2304
constexpr int HEADS_ = 8;
#define INV_SQRT_DH 0.17677669529663688f

__device__ __forceinline__ ushort_t bf16_rn(float x) {
  unsigned u = __float_as_uint(x);
  return (ushort_t)((u + 0x7fffu + ((u >> 16) & 1u)) >> 16);
}

// ---------------------------------------------------------------------------
// Kernel 1 (fused both layers x3 tensors): in [b][C][S] -> L1 -> LDS -> L2 ->
// bf16 hi/lo planes. z=0: Q [b][s][C]; z=1: K [b][s][C]; z=2: V^T [b][C][s].
// grid (72, B, 3), block 256. LDS 66 KB -> 2 blocks/CU.
// ---------------------------------------------------------------------------
__global__ __launch_bounds__(256) void k_mlpf(
    const float* __restrict__ x, const float* __restrict__ ref,
    const float* __restrict__ qW1, const float* __restrict__ qb1,
    const float* __restrict__ qW2, const float* __restrict__ qb2,
    const float* __restrict__ kW1, const float* __restrict__ kb1,
    const float* __restrict__ kW2, const float* __restrict__ kb2,
    const float* __restrict__ vW1, const float* __restrict__ vb1,
    const float* __restrict__ vW2, const float* __restrict__ vb2,
    ushort_t* __restrict__ Qh, ushort_t* __restrict__ Ql,
    ushort_t* __restrict__ Kh, ushort_t* __restrict__ Kl,
    ushort_t* __restrict__ VhT, ushort_t* __restrict__ VlT) {
  __shared__ __align__(16) float in_s[32][260];
  __shared__ __align__(16) float h_s[32][260];
  const int tid = threadIdx.x;
  const int s0 = blockIdx.x * 32;
  const int b  = blockIdx.y;
  const int z  = blockIdx.z;
  const float* in = (z == 0) ? x : ref;
  const float* W1 = (z == 0) ? qW1 : (z == 1) ? kW1 : vW1;
  const float* b1 = (z == 0) ? qb1 : (z == 1) ? kb1 : vb1;
  const float* W2 = (z == 0) ? qW2 : (z == 1) ? kW2 : vW2;
  const float* b2 = (z == 0) ? qb2 : (z == 1) ? kb2 : vb2;

  for (int idx = tid; idx < 32 * 256; idx += 256) {
    int ci = idx >> 5, r = idx & 31;
    in_s[r][ci] = in[((size_t)b * C_ + ci) * S_TOT + s0 + r];
  }
  __syncthreads();

  const int co = tid;
  float acc[32];
#pragma unroll
  for (int r = 0; r < 32; ++r) acc[r] = 0.f;
  for (int c4 = 0; c4 < 64; ++c4) {
    const float w0 = W1[(c4 * 4 + 0) * C_ + co];
    const float w1 = W1[(c4 * 4 + 1) * C_ + co];
    const float w2 = W1[(c4 * 4 + 2) * C_ + co];
    const float w3 = W1[(c4 * 4 + 3) * C_ + co];
#pragma unroll
    for (int r = 0; r < 32; ++r) {
      float4 a = *(const float4*)&in_s[r][c4 * 4];
      acc[r] = fmaf(a.x, w0, fmaf(a.y, w1, fmaf(a.z, w2, fmaf(a.w, w3, acc[r]))));
    }
  }
  {
    const float bi = b1[co];
#pragma unroll
    for (int r = 0; r < 32; ++r) h_s[r][co] = fmaxf(acc[r] + bi, 0.f);
  }
  __syncthreads();

#pragma unroll
  for (int r = 0; r < 32; ++r) acc[r] = 0.f;
  for (int c4 = 0; c4 < 64; ++c4) {
    const float w0 = W2[(c4 * 4 + 0) * C_ + co];
    const float w1 = W2[(c4 * 4 + 1) * C_ + co];
    const float w2 = W2[(c4 * 4 + 2) * C_ + co];
    const float w3 = W2[(c4 * 4 + 3) * C_ + co];
#pragma unroll
    for (int r = 0; r < 32; ++r) {
      float4 a = *(const float4*)&h_s[r][c4 * 4];
      acc[r] = fmaf(a.x, w0, fmaf(a.y, w1, fmaf(a.z, w2, fmaf(a.w, w3, acc[r]))));
    }
  }
  const float bi = b2[co];

  if (z < 2) {
    ushort_t* Ph = (z == 0) ? Qh : Kh;
    ushort_t* Pl = (z == 0) ? Ql : Kl;
#pragma unroll 4
    for (int r = 0; r < 32; ++r) {
      float y = fmaxf(acc[r] + bi, 0.f);
      ushort_t h = bf16_rn(y);
      float hf = __uint_as_float((unsigned)h << 16);
      ushort_t l = bf16_rn(y - hf);
      size_t o = ((size_t)b * S_TOT + s0 + r) * C_ + co;
      Ph[o] = h;
      Pl[o] = l;
    }
  } else {
    ushort_t hs[32], ls[32];
#pragma unroll
    for (int r = 0; r < 32; ++r) {
      float y = fmaxf(acc[r] + bi, 0.f);
      ushort_t h = bf16_rn(y);
      float hf = __uint_as_float((unsigned)h << 16);
      hs[r] = h;
      ls[r] = bf16_rn(y - hf);
    }
    size_t base = ((size_t)b * C_ + co) * S_TOT + s0;
#pragma unroll
    for (int k = 0; k < 4; ++k) {
      u16x8 hv, lv;
#pragma unroll
      for (int q = 0; q < 8; ++q) { hv[q] = hs[k * 8 + q]; lv[q] = ls[k * 8 + q]; }
      *(u16x8*)(VhT + base + k * 8) = hv;
      *(u16x8*)(VlT + base + k * 8) = lv;
    }
  }
}

// ---------------------------------------------------------------------------
// Kernel 2 (MFMA): scores + top-1-over-heads mask -> U bf16 + Z partials.
// (verified structure, unchanged)
// ---------------------------------------------------------------------------
__global__ __launch_bounds__(256) void k_scores_mfma(
    const ushort_t* __restrict__ Qh, const ushort_t* __restrict__ Ql,
    const ushort_t* __restrict__ Kh, const ushort_t* __restrict__ Kl,
    ushort_t* __restrict__ U, float* __restrict__ st_z) {
  __shared__ __align__(16) uint4 kh_s[64 * 32];
  __shared__ __align__(16) uint4 kl_s[64 * 32];
  const int tid = threadIdx.x;
  const int w = tid >> 6, lane = tid & 63;
  const int li = lane & 15, kg = lane >> 4;
  const int i0 = blockIdx.x * 64;
  const int js = blockIdx.y;
  const int b  = blockIdx.z;
  const int jbase = js * 576;

  s8v ahi[8], alo[8];
  {
    const ushort_t* qh = Qh + ((size_t)b * S_TOT + i0 + w * 16 + li) * C_ + kg * 8;
    const ushort_t* ql = Ql + ((size_t)b * S_TOT + i0 + w * 16 + li) * C_ + kg * 8;
#pragma unroll
    for (int h = 0; h < 8; ++h) {
      ahi[h] = __builtin_bit_cast(s8v, *(const uint4*)(qh + h * 32));
      alo[h] = __builtin_bit_cast(s8v, *(const uint4*)(ql + h * 32));
    }
  }

  float zacc[4][8];
#pragma unroll
  for (int r = 0; r < 4; ++r)
#pragma unroll
    for (int h = 0; h < 8; ++h) zacc[r][h] = 0.f;

  for (int jt = 0; jt < 9; ++jt) {
    const int j0 = jbase + jt * 64;
    __syncthreads();
    for (int e = tid; e < 2048; e += 256) {
      int r = e >> 5, c = e & 31;
      size_t goff = ((size_t)b * S_TOT + j0 + r) * C_ + c * 8;
      int cs = c ^ (r & 7);
      kh_s[r * 32 + cs] = *(const uint4*)(Kh + goff);
      kl_s[r * 32 + cs] = *(const uint4*)(Kl + goff);
    }
    __syncthreads();

#pragma unroll
    for (int jsub = 0; jsub < 4; ++jsub) {
      const int rj = jsub * 16 + li;
      f32x4 sc[8];
#pragma unroll
      for (int h = 0; h < 8; ++h) {
        const int cs = (h * 4 + kg) ^ (rj & 7);
        s8v bhi = __builtin_bit_cast(s8v, kh_s[rj * 32 + cs]);
        s8v blo = __builtin_bit_cast(s8v, kl_s[rj * 32 + cs]);
        f32x4 acc = {0.f, 0.f, 0.f, 0.f};
        acc = __builtin_amdgcn_mfma_f32_16x16x32_bf16(ahi[h], bhi, acc, 0, 0, 0);
        acc = __builtin_amdgcn_mfma_f32_16x16x32_bf16(ahi[h], blo, acc, 0, 0, 0);
        acc = __builtin_amdgcn_mfma_f32_16x16x32_bf16(alo[h], bhi, acc, 0, 0, 0);
        sc[h] = acc;
      }
      const int jcol = j0 + jsub * 16 + li;
#pragma unroll
      for (int reg = 0; reg < 4; ++reg) {
        float s8_[8];
        float thr = -1e30f;
#pragma unroll
        for (int h = 0; h < 8; ++h) {
          s8_[h] = sc[h][reg] * INV_SQRT_DH;
          thr = fmaxf(thr, s8_[h]);
        }
        const int i = i0 + w * 16 + kg * 4 + reg;
#pragma unroll
        for (int h = 0; h < 8; ++h) {
          float mv = s8_[h] < thr ? -1e18f : s8_[h];
          float uf = __expf(mv);            // 0 exactly when masked
          ushort_t ub = bf16_rn(uf);
          U[((size_t)((b * 8 + h) * S_TOT + i)) * S_TOT + jcol] = ub;
          zacc[reg][h] += __uint_as_float((unsigned)ub << 16);
        }
      }
    }
  }

#pragma unroll
  for (int reg = 0; reg < 4; ++reg) {
#pragma unroll
    for (int h = 0; h < 8; ++h) {
      float z = zacc[reg][h];
      z += __shfl_xor(z, 1);
      z += __shfl_xor(z, 2);
      z += __shfl_xor(z, 4);
      z += __shfl_xor(z, 8);
      if (li == 0) {
        const int i = i0 + w * 16 + kg * 4 + reg;
        size_t sidx = ((size_t)(js * B_ + b) * HEADS_ + h) * S_TOT + i;
        st_z[sidx] = z;
      }
    }
  }
}

// ---------------------------------------------------------------------------
// Kernel 3: probs = U/Z + partial ctx via bf16 MFMA, j-split 2-way.
// grid (36 i-tiles, 8 h, 4 = jc*2+b), block 256 (4 waves).
// Each block covers 18 j-tiles; partial ctx (f32, iz applied, [b][s][c]
// layout) -> Cp[jc]. Reg-prefetch pipeline, LDS 26.5 KB -> ~4-5 blocks/CU.
// ---------------------------------------------------------------------------
__global__ __launch_bounds__(256) void k_pv5(const ushort_t* __restrict__ U,
                                             const float* __restrict__ st_z,
                                             const ushort_t* __restrict__ VhT,
                                             const ushort_t* __restrict__ VlT,
                                             float* __restrict__ probs,
                                             float* __restrict__ part0,
                                             float* __restrict__ part1) {
  __shared__ __align__(16) ushort_t u_s[2][64 * 64];
  __shared__ __align__(16) ushort_t vh_s[2][32 * 64];
  __shared__ __align__(16) ushort_t vl_s[2][32 * 64];
  __shared__ float row_iz[64];
  __shared__ int   row_sub[64];
  const int tid = threadIdx.x;
  const int w = tid >> 6, lane = tid & 63;
  const int li = lane & 15, kg = lane >> 4;
  const int i0 = blockIdx.x * 64;
  const int h  = blockIdx.y;
  const int z  = blockIdx.z;
  const int b  = z & 1;
  const int jc = z >> 1;
  float* part = jc ? part1 : part0;
  const int jlo = jc * 1152;

  if (tid < 64) {
    const int i = i0 + tid;
    float Z = 0.f;
#pragma unroll
    for (int js = 0; js < 4; ++js)
      Z += st_z[((size_t)(js * B_ + b) * HEADS_ + h) * S_TOT + i];
    if (Z == 0.f) { row_iz[tid] = 1.0f / (float)S_TOT; row_sub[tid] = 1; }
    else          { row_iz[tid] = 1.0f / Z;            row_sub[tid] = 0; }
  }

  const ushort_t* ub = U + ((size_t)((b * 8 + h) * S_TOT + i0)) * S_TOT;
  float* pb = probs + ((size_t)((b * 8 + h) * S_TOT + i0)) * S_TOT;
  const ushort_t* vhb = VhT + ((size_t)(b * C_ + h * 32)) * S_TOT;
  const ushort_t* vlb = VlT + ((size_t)(b * C_ + h * 32)) * S_TOT;

  const int r0_  = tid >> 3,         c8_0 = tid & 7;
  const int r1_  = (tid + 256) >> 3, c8_1 = tid & 7;
  const int dr_  = tid >> 3, c8v = tid & 7;
  const size_t uo0 = (size_t)r0_ * S_TOT + c8_0 * 8 + jlo;
  const size_t uo1 = (size_t)r1_ * S_TOT + c8_1 * 8 + jlo;
  const size_t vo  = (size_t)(dr_ & 31) * S_TOT + c8v * 8 + jlo;

  f32x4 acc[2];
  acc[0] = (f32x4){0.f, 0.f, 0.f, 0.f};
  acc[1] = (f32x4){0.f, 0.f, 0.f, 0.f};

  u16x8 ur0 = *(const u16x8*)(ub + uo0);
  u16x8 ur1 = *(const u16x8*)(ub + uo1);
  u16x8 vhr = *(const u16x8*)(vhb + vo);
  u16x8 vlr = *(const u16x8*)(vlb + vo);
  __syncthreads();

  for (int t = 0; t < 18; ++t) {
    const int j0 = jlo + t * 64;
    const int buf = t & 1;

    {
      u16x8 uu = ur0;
      if (row_sub[r0_]) uu = (u16x8){0x3F80,0x3F80,0x3F80,0x3F80,0x3F80,0x3F80,0x3F80,0x3F80};
      float iz = row_iz[r0_];
      float4 p0, p1;
      p0.x = __uint_as_float((unsigned)uu[0] << 16) * iz;
      p0.y = __uint_as_float((unsigned)uu[1] << 16) * iz;
      p0.z = __uint_as_float((unsigned)uu[2] << 16) * iz;
      p0.w = __uint_as_float((unsigned)uu[3] << 16) * iz;
      p1.x = __uint_as_float((unsigned)uu[4] << 16) * iz;
      p1.y = __uint_as_float((unsigned)uu[5] << 16) * iz;
      p1.z = __uint_as_float((unsigned)uu[6] << 16) * iz;
      p1.w = __uint_as_float((unsigned)uu[7] << 16) * iz;
      float* gp = pb + (size_t)r0_ * S_TOT + j0 + c8_0 * 8;
      *(float4*)gp = p0;
      *(float4*)(gp + 4) = p1;
      *(u16x8*)&u_s[buf][r0_ * 64 + (c8_0 ^ (r0_ & 7)) * 8] = uu;
    }
    {
      u16x8 uu = ur1;
      if (row_sub[r1_]) uu = (u16x8){0x3F80,0x3F80,0x3F80,0x3F80,0x3F80,0x3F80,0x3F80,0x3F80};
      float iz = row_iz[r1_];
      float4 p0, p1;
      p0.x = __uint_as_float((unsigned)uu[0] << 16) * iz;
      p0.y = __uint_as_float((unsigned)uu[1] << 16) * iz;
      p0.z = __uint_as_float((unsigned)uu[2] << 16) * iz;
      p0.w = __uint_as_float((unsigned)uu[3] << 16) * iz;
      p1.x = __uint_as_float((unsigned)uu[4] << 16) * iz;
      p1.y = __uint_as_float((unsigned)uu[5] << 16) * iz;
      p1.z = __uint_as_float((unsigned)uu[6] << 16) * iz;
      p1.w = __uint_as_float((unsigned)uu[7] << 16) * iz;
      float* gp = pb + (size_t)r1_ * S_TOT + j0 + c8_1 * 8;
      *(float4*)gp = p0;
      *(float4*)(gp + 4) = p1;
      *(u16x8*)&u_s[buf][r1_ * 64 + (c8_1 ^ (r1_ & 7)) * 8] = uu;
    }
    *(u16x8*)&vh_s[buf][(dr_ & 31) * 64 + (c8v ^ (dr_ & 7)) * 8] = vhr;
    *(u16x8*)&vl_s[buf][(dr_ & 31) * 64 + (c8v ^ (dr_ & 7)) * 8] = vlr;

    if (t < 17) {
      const size_t j1 = (size_t)(t + 1) * 64;
      ur0 = *(const u16x8*)(ub + uo0 + j1);
      ur1 = *(const u16x8*)(ub + uo1 + j1);
      vhr = *(const u16x8*)(vhb + vo + j1);
      vlr = *(const u16x8*)(vlb + vo + j1);
    }
    __syncthreads();

    {
      const int row = w * 16 + li;
      const int rs = li & 7;
      s8v a0 = __builtin_bit_cast(s8v, *(const uint4*)&u_s[buf][row * 64 + ((kg)     ^ rs) * 8]);
      s8v a1 = __builtin_bit_cast(s8v, *(const uint4*)&u_s[buf][row * 64 + ((4 + kg) ^ rs) * 8]);
#pragma unroll
      for (int dh = 0; dh < 2; ++dh) {
        const int d = dh * 16 + li;
        const int ds_ = li & 7;
        s8v bh0 = __builtin_bit_cast(s8v, *(const uint4*)&vh_s[buf][d * 64 + ((kg)     ^ ds_) * 8]);
        s8v bl0 = __builtin_bit_cast(s8v, *(const uint4*)&vl_s[buf][d * 64 + ((kg)     ^ ds_) * 8]);
        s8v bh1 = __builtin_bit_cast(s8v, *(const uint4*)&vh_s[buf][d * 64 + ((4 + kg) ^ ds_) * 8]);
        s8v bl1 = __builtin_bit_cast(s8v, *(const uint4*)&vl_s[buf][d * 64 + ((4 + kg) ^ ds_) * 8]);
        acc[dh] = __builtin_amdgcn_mfma_f32_16x16x32_bf16(a0, bh0, acc[dh], 0, 0, 0);
        acc[dh] = __builtin_amdgcn_mfma_f32_16x16x32_bf16(a0, bl0, acc[dh], 0, 0, 0);
        acc[dh] = __builtin_amdgcn_mfma_f32_16x16x32_bf16(a1, bh1, acc[dh], 0, 0, 0);
        acc[dh] = __builtin_amdgcn_mfma_f32_16x16x32_bf16(a1, bl1, acc[dh], 0, 0, 0);
      }
    }
  }

  // epilogue: partial ctx (f32, iz applied) in [b][s][c] layout, coalesced in li
#pragma unroll
  for (int dh = 0; dh < 2; ++dh) {
#pragma unroll
    for (int reg = 0; reg < 4; ++reg) {
      const int irow = w * 16 + kg * 4 + reg;
      float v = acc[dh][reg] * row_iz[irow];
      part[((size_t)b * S_TOT + i0 + irow) * C_ + h * 32 + dh * 16 + li] = v;
    }
  }
}

// ---------------------------------------------------------------------------
// Kernel 3b: ctxT hi/lo = split(part0 + part1) (elementwise, [b][s][c])
// ---------------------------------------------------------------------------
__global__ __launch_bounds__(256) void k_pvred(const float* __restrict__ p0,
                                               const float* __restrict__ p1,
                                               ushort_t* __restrict__ cTh,
                                               ushort_t* __restrict__ cTl) {
  size_t i4 = ((size_t)blockIdx.x * 256 + threadIdx.x) * 4;
  float4 a = *(const float4*)(p0 + i4);
  float4 b = *(const float4*)(p1 + i4);
  float v[4] = {a.x + b.x, a.y + b.y, a.z + b.z, a.w + b.w};
  ushort4 hv, lv;
  ushort_t* hp = (ushort_t*)&hv;
  ushort_t* lp = (ushort_t*)&lv;
#pragma unroll
  for (int q = 0; q < 4; ++q) {
    ushort_t h = bf16_rn(v[q]);
    float hf = __uint_as_float((unsigned)h << 16);
    hp[q] = h;
    lp[q] = bf16_rn(v[q] - hf);
  }
  *(ushort4*)(cTh + i4) = hv;
  *(ushort4*)(cTl + i4) = lv;
}

// ---------------------------------------------------------------------------
// Kernel 4a: repack+split conv weights -> Wh/Wl[tap][co][ci]
// ---------------------------------------------------------------------------
__global__ __launch_bounds__(256) void k_repackW_split(const float* __restrict__ W,
                                                       ushort_t* __restrict__ Wh,
                                                       ushort_t* __restrict__ Wl) {
  const int co = blockIdx.x, tap = blockIdx.y, ci = threadIdx.x;
  float v = W[((size_t)co * 256 + ci) * 9 + tap];
  ushort_t h = bf16_rn(v);
  float r = __uint_as_float((unsigned)h << 16);
  ushort_t l = bf16_rn(v - r);
  size_t o = ((size_t)tap * 256 + co) * 256 + ci;
  Wh[o] = h;
  Wl[o] = l;
}

// ---------------------------------------------------------------------------
// Kernel 4b: conv MFMA v2 — input pre-split/transposed bf16 [b][s][c].
// grid (8 co-tiles, 24 y-pairs, 4 = b*2+ch), block 256; ch = ci half.
// ---------------------------------------------------------------------------
__global__ __launch_bounds__(256) void k_conv_mfma2(
    const ushort_t* __restrict__ inTh, const ushort_t* __restrict__ inTl,
    const ushort_t* __restrict__ Wh, const ushort_t* __restrict__ Wl,
    float* __restrict__ part0, float* __restrict__ part1) {
  __shared__ __align__(16) ushort_t in_sh[4 * 50 * 40];
  __shared__ __align__(16) ushort_t in_sl[4 * 50 * 40];
  const int tid = threadIdx.x;
  const int w = tid >> 6, lane = tid & 63;
  const int li = lane & 15, kg = lane >> 4;
  const int cg = w & 1, rw = w >> 1;
  const int co0 = blockIdx.x * 32;
  const int y0  = blockIdx.y * 2;
  const int z   = blockIdx.z;
  const int b = z >> 1, ch = z & 1;
  float* part = ch ? part1 : part0;

  for (int e = tid; e < 320; e += 256) {
    int sr = e / 80, rem = e % 80;
    int xl = (rem / 40) * 49, ci = rem % 40;
    in_sh[(sr * 50 + xl) * 40 + ci] = 0;
    in_sl[(sr * 50 + xl) * 40 + ci] = 0;
  }

  f32x4 acc[3];
#pragma unroll
  for (int xg = 0; xg < 3; ++xg) acc[xg] = (f32x4){0.f, 0.f, 0.f, 0.f};

  for (int c8 = 0; c8 < 4; ++c8) {
    const int ci0 = ch * 128 + c8 * 32;
    __syncthreads();
#pragma unroll
    for (int t = 0; t < 3; ++t) {
      int id = t * 256 + tid;
      int cig = id & 3;
      int xx  = (id >> 2) % 48;
      int sr  = id / 192;
      int gr  = y0 - 1 + sr;
      u16x8 vh = {0,0,0,0,0,0,0,0}, vl = {0,0,0,0,0,0,0,0};
      if (gr >= 0 && gr < 48) {
        size_t go = ((size_t)b * S_TOT + gr * 48 + xx) * C_ + ci0 + cig * 8;
        vh = *(const u16x8*)(inTh + go);
        vl = *(const u16x8*)(inTl + go);
      }
      int lo = (sr * 50 + xx + 1) * 40 + cig * 8;
      *(u16x8*)&in_sh[lo] = vh;
      *(u16x8*)&in_sl[lo] = vl;
    }
    __syncthreads();

#pragma unroll
    for (int ky = 0; ky < 3; ++ky) {
      const int srr = rw + ky;
#pragma unroll
      for (int kx = 0; kx < 3; ++kx) {
        const int tap = ky * 3 + kx;
        size_t wo = ((size_t)tap * 256 + co0 + cg * 16 + li) * 256 + ci0 + kg * 8;
        s8v ah = __builtin_bit_cast(s8v, *(const uint4*)(Wh + wo));
        s8v al = __builtin_bit_cast(s8v, *(const uint4*)(Wl + wo));
#pragma unroll
        for (int xg = 0; xg < 3; ++xg) {
          const int xl = xg * 16 + li + kx;
          s8v bh = __builtin_bit_cast(s8v, *(const uint4*)&in_sh[(srr * 50 + xl) * 40 + kg * 8]);
          s8v bl = __builtin_bit_cast(s8v, *(const uint4*)&in_sl[(srr * 50 + xl) * 40 + kg * 8]);
          acc[xg] = __builtin_amdgcn_mfma_f32_16x16x32_bf16(ah, bh, acc[xg], 0, 0, 0);
          acc[xg] = __builtin_amdgcn_mfma_f32_16x16x32_bf16(ah, bl, acc[xg], 0, 0, 0);
          acc[xg] = __builtin_amdgcn_mfma_f32_16x16x32_bf16(al, bh, acc[xg], 0, 0, 0);
        }
      }
    }
  }

  const int orow = y0 + rw;
#pragma unroll
  for (int reg = 0; reg < 4; ++reg) {
    const int co = co0 + cg * 16 + kg * 4 + reg;
    float* op = part + ((size_t)(b * 256 + co) * 48 + orow) * 48 + li;
#pragma unroll
    for (int xg = 0; xg < 3; ++xg) op[xg * 16] = acc[xg][reg];
  }
}

// ---------------------------------------------------------------------------
// Kernel 4c: y = selu(Cp0+Cp1+bias), transpose+split -> t1T hi/lo [b][s][c].
// grid (36 s-tiles, 4 co-tiles, B).
// ---------------------------------------------------------------------------
__global__ __launch_bounds__(256) void k_act_t(const float* __restrict__ p0,
                                               const float* __restrict__ p1,
                                               const float* __restrict__ bias,
                                               ushort_t* __restrict__ outTh,
                                               ushort_t* __restrict__ outTl) {
  __shared__ __align__(16) float t_s[64][65];
  const int tid = threadIdx.x;
  const int s0 = blockIdx.x * 64;
  const int co0 = blockIdx.y * 64;
  const int b  = blockIdx.z;

#pragma unroll
  for (int k = 0; k < 16; ++k) {
    int idx = tid + k * 256;
    int r = idx >> 6, c = idx & 63;
    size_t a = ((size_t)(b * 256 + co0 + r)) * S_TOT + s0 + c;
    float v = p0[a] + p1[a] + bias[co0 + r];
    v = 1.0507009873554805f * (v > 0.f ? v : 1.6732632423543772f * expm1f(v));
    t_s[r][c] = v;
  }
  __syncthreads();
#pragma unroll
  for (int k = 0; k < 16; ++k) {
    int idx = tid + k * 256;
    int p = idx >> 6, c = idx & 63;
    float v = t_s[c][p];
    ushort_t h = bf16_rn(v);
    float hf = __uint_as_float((unsigned)h << 16);
    ushort_t l = bf16_rn(v - hf);
    size_t o = ((size_t)b * S_TOT + s0 + p) * C_ + co0 + c;
    outTh[o] = h;
    outTl[o] = l;
  }
}

// ---------------------------------------------------------------------------
// Kernel 4d: out = Cp0 + Cp1 + bias (f32, no act)
// ---------------------------------------------------------------------------
__global__ __launch_bounds__(256) void k_act2(const float* __restrict__ p0,
                                              const float* __restrict__ p1,
                                              const float* __restrict__ bias,
                                              float* __restrict__ out) {
  size_t i4 = ((size_t)blockIdx.x * 256 + threadIdx.x) * 4;
  float4 a = *(const float4*)(p0 + i4);
  float4 b = *(const float4*)(p1 + i4);
  int co = (int)((i4 / (size_t)S_TOT) & 255);
  float bi = bias[co];
  float4 o;
  o.x = a.x + b.x + bi; o.y = a.y + b.y + bi;
  o.z = a.z + b.z + bi; o.w = a.w + b.w + bi;
  *(float4*)(out + i4) = o;
}

// ---------------------------------------------------------------------------
extern "C" void kernel_launch(void* const* d_in, const int* in_sizes, int n_in,
                              void* d_out, int out_size, void* d_ws, size_t ws_size,
                              hipStream_t stream) {
  const float* x   = (const float*)d_in[0];
  const float* ref = (const float*)d_in[1];
  const float* qW1 = (const float*)d_in[2];
  const float* qb1 = (const float*)d_in[3];
  const float* qW2 = (const float*)d_in[4];
  const float* qb2 = (const float*)d_in[5];
  const float* kW1 = (const float*)d_in[6];
  const float* kb1 = (const float*)d_in[7];
  const float* kW2 = (const float*)d_in[8];
  const float* kb2 = (const float*)d_in[9];
  const float* vW1 = (const float*)d_in[10];
  const float* vb1 = (const float*)d_in[11];
  const float* vW2 = (const float*)d_in[12];
  const float* vb2 = (const float*)d_in[13];
  const float* c1W = (const float*)d_in[14];
  const float* c1b = (const float*)d_in[15];
  const float* c2W = (const float*)d_in[16];
  const float* c2b = (const float*)d_in[17];

  float* out = (float*)d_out;
  float* probs = out + (size_t)B_ * C_ * S_TOT;       // [B][H][S][S]
  float* ws = (float*)d_ws;
  const size_t BSC = (size_t)B_ * S_TOT * C_;         // 1,179,648
  const size_t STATS = (size_t)4 * B_ * HEADS_ * S_TOT;
  const size_t WTSZ = (size_t)256 * 9 * 256;

  float* stz = ws;
  float* Cp0 = stz + STATS;
  float* Cp1 = Cp0 + BSC;
  float* endf = Cp1 + BSC;

  ushort_t* Qh  = (ushort_t*)endf;
  ushort_t* Ql  = Qh + BSC;
  ushort_t* Kh  = Ql + BSC;
  ushort_t* Kl  = Kh + BSC;
  ushort_t* VhT = Kl + BSC;
  ushort_t* VlT = VhT + BSC;
  ushort_t* cTh = VlT + BSC;
  ushort_t* cTl = cTh + BSC;
  ushort_t* t1h = cTl + BSC;
  ushort_t* t1l = t1h + BSC;
  ushort_t* Wh1 = t1l + BSC;
  ushort_t* Wl1 = Wh1 + WTSZ;
  ushort_t* Wh2 = Wl1 + WTSZ;
  ushort_t* Wl2 = Wh2 + WTSZ;
  ushort_t* Ubuf = Wl2 + WTSZ;   // ~170 MB

  dim3 blk(256);
  k_repackW_split<<<dim3(256, 9), blk, 0, stream>>>(c1W, Wh1, Wl1);
  k_repackW_split<<<dim3(256, 9), blk, 0, stream>>>(c2W, Wh2, Wl2);

  k_mlpf<<<dim3(72, B_, 3), blk, 0, stream>>>(x, ref,
                                              qW1, qb1, qW2, qb2,
                                              kW1, kb1, kW2, kb2,
                                              vW1, vb1, vW2, vb2,
                                              Qh, Ql, Kh, Kl, VhT, VlT);

  k_scores_mfma<<<dim3(36, 4, B_), blk, 0, stream>>>(Qh, Ql, Kh, Kl, Ubuf, stz);

  k_pv5<<<dim3(36, 8, 4), blk, 0, stream>>>(Ubuf, stz, VhT, VlT, probs, Cp0, Cp1);
  k_pvred<<<dim3((int)(BSC / 1024)), blk, 0, stream>>>(Cp0, Cp1, cTh, cTl);

  dim3 gconv(8, 24, 2 * B_);
  k_conv_mfma2<<<gconv, blk, 0, stream>>>(cTh, cTl, Wh1, Wl1, Cp0, Cp1);
  k_act_t<<<dim3(36, 4, B_), blk, 0, stream>>>(Cp0, Cp1, c1b, t1h, t1l);
  k_conv_mfma2<<<gconv, blk, 0, stream>>>(t1h, t1l, Wh2, Wl2, Cp0, Cp1);
  k_act2<<<dim3((int)(BSC / 1024)), blk, 0, stream>>>(Cp0, Cp1, c2b, out);
}

// Round 11
// 454.235 us; speedup vs baseline: 2.4476x; 1.0770x over previous
//
#include <hip/hip_runtime.h>
#include <hip/hip_bf16.h>

typedef unsigned short ushort_t;
typedef short s8v __attribute__((ext_vector_type(8)));      // 8 bf16 bit-patterns
typedef ushort_t u16x8 __attribute__((ext_vector_type(8))); // 8 ushorts (16B)
typedef float f32x4 __attribute__((ext_vector_type(4)));

// Problem constants
constexpr int B_ = 2;
constexpr int C_ = 256;
constexpr int S_TOT = 48 * 48;   // 2304
constexpr int HEADS_ = 8;
constexpr int JSPLIT = 12;       // scores j-chunks (Z partials)
#define INV_SQRT_DH 0.17677669529663688f

__device__ __forceinline__ ushort_t bf16_rn(float x) {
  unsigned u = __float_as_uint(x);
  return (ushort_t)((u + 0x7fffu + ((u >> 16) & 1u)) >> 16);
}

// ---------------------------------------------------------------------------
// Kernel 1 (fused both layers x3 tensors): in [b][C][S] -> L1 -> LDS -> L2 ->
// bf16 hi/lo planes. z=0: Q [b][s][C]; z=1: K [b][s][C]; z=2: V^T [b][C][s].
// grid (72, B, 3), block 256.
// ---------------------------------------------------------------------------
__global__ __launch_bounds__(256) void k_mlpf(
    const float* __restrict__ x, const float* __restrict__ ref,
    const float* __restrict__ qW1, const float* __restrict__ qb1,
    const float* __restrict__ qW2, const float* __restrict__ qb2,
    const float* __restrict__ kW1, const float* __restrict__ kb1,
    const float* __restrict__ kW2, const float* __restrict__ kb2,
    const float* __restrict__ vW1, const float* __restrict__ vb1,
    const float* __restrict__ vW2, const float* __restrict__ vb2,
    ushort_t* __restrict__ Qh, ushort_t* __restrict__ Ql,
    ushort_t* __restrict__ Kh, ushort_t* __restrict__ Kl,
    ushort_t* __restrict__ VhT, ushort_t* __restrict__ VlT) {
  __shared__ __align__(16) float in_s[32][260];
  __shared__ __align__(16) float h_s[32][260];
  const int tid = threadIdx.x;
  const int s0 = blockIdx.x * 32;
  const int b  = blockIdx.y;
  const int z  = blockIdx.z;
  const float* in = (z == 0) ? x : ref;
  const float* W1 = (z == 0) ? qW1 : (z == 1) ? kW1 : vW1;
  const float* b1 = (z == 0) ? qb1 : (z == 1) ? kb1 : vb1;
  const float* W2 = (z == 0) ? qW2 : (z == 1) ? kW2 : vW2;
  const float* b2 = (z == 0) ? qb2 : (z == 1) ? kb2 : vb2;

  for (int idx = tid; idx < 32 * 256; idx += 256) {
    int ci = idx >> 5, r = idx & 31;
    in_s[r][ci] = in[((size_t)b * C_ + ci) * S_TOT + s0 + r];
  }
  __syncthreads();

  const int co = tid;
  float acc[32];
#pragma unroll
  for (int r = 0; r < 32; ++r) acc[r] = 0.f;
  for (int c4 = 0; c4 < 64; ++c4) {
    const float w0 = W1[(c4 * 4 + 0) * C_ + co];
    const float w1 = W1[(c4 * 4 + 1) * C_ + co];
    const float w2 = W1[(c4 * 4 + 2) * C_ + co];
    const float w3 = W1[(c4 * 4 + 3) * C_ + co];
#pragma unroll
    for (int r = 0; r < 32; ++r) {
      float4 a = *(const float4*)&in_s[r][c4 * 4];
      acc[r] = fmaf(a.x, w0, fmaf(a.y, w1, fmaf(a.z, w2, fmaf(a.w, w3, acc[r]))));
    }
  }
  {
    const float bi = b1[co];
#pragma unroll
    for (int r = 0; r < 32; ++r) h_s[r][co] = fmaxf(acc[r] + bi, 0.f);
  }
  __syncthreads();

#pragma unroll
  for (int r = 0; r < 32; ++r) acc[r] = 0.f;
  for (int c4 = 0; c4 < 64; ++c4) {
    const float w0 = W2[(c4 * 4 + 0) * C_ + co];
    const float w1 = W2[(c4 * 4 + 1) * C_ + co];
    const float w2 = W2[(c4 * 4 + 2) * C_ + co];
    const float w3 = W2[(c4 * 4 + 3) * C_ + co];
#pragma unroll
    for (int r = 0; r < 32; ++r) {
      float4 a = *(const float4*)&h_s[r][c4 * 4];
      acc[r] = fmaf(a.x, w0, fmaf(a.y, w1, fmaf(a.z, w2, fmaf(a.w, w3, acc[r]))));
    }
  }
  const float bi = b2[co];

  if (z < 2) {
    ushort_t* Ph = (z == 0) ? Qh : Kh;
    ushort_t* Pl = (z == 0) ? Ql : Kl;
#pragma unroll 4
    for (int r = 0; r < 32; ++r) {
      float y = fmaxf(acc[r] + bi, 0.f);
      ushort_t h = bf16_rn(y);
      float hf = __uint_as_float((unsigned)h << 16);
      ushort_t l = bf16_rn(y - hf);
      size_t o = ((size_t)b * S_TOT + s0 + r) * C_ + co;
      Ph[o] = h;
      Pl[o] = l;
    }
  } else {
    ushort_t hs[32], ls[32];
#pragma unroll
    for (int r = 0; r < 32; ++r) {
      float y = fmaxf(acc[r] + bi, 0.f);
      ushort_t h = bf16_rn(y);
      float hf = __uint_as_float((unsigned)h << 16);
      hs[r] = h;
      ls[r] = bf16_rn(y - hf);
    }
    size_t base = ((size_t)b * C_ + co) * S_TOT + s0;
#pragma unroll
    for (int k = 0; k < 4; ++k) {
      u16x8 hv, lv;
#pragma unroll
      for (int q = 0; q < 8; ++q) { hv[q] = hs[k * 8 + q]; lv[q] = ls[k * 8 + q]; }
      *(u16x8*)(VhT + base + k * 8) = hv;
      *(u16x8*)(VlT + base + k * 8) = lv;
    }
  }
}

// ---------------------------------------------------------------------------
// Kernel 2 (MFMA): scores + top-1-over-heads mask -> U bf16 + Z partials.
// grid (36 i-tiles, JSPLIT=12 j-chunks, B) = 864 blocks -> 2 blocks/CU
// resident (64 KB LDS), 2 waves/SIMD: latency hiding (was 1 wave/SIMD at
// js=4/288 blocks — the round-10 bottleneck).
// ---------------------------------------------------------------------------
__global__ __launch_bounds__(256) void k_scores_mfma(
    const ushort_t* __restrict__ Qh, const ushort_t* __restrict__ Ql,
    const ushort_t* __restrict__ Kh, const ushort_t* __restrict__ Kl,
    ushort_t* __restrict__ U, float* __restrict__ st_z) {
  __shared__ __align__(16) uint4 kh_s[64 * 32];
  __shared__ __align__(16) uint4 kl_s[64 * 32];
  const int tid = threadIdx.x;
  const int w = tid >> 6, lane = tid & 63;
  const int li = lane & 15, kg = lane >> 4;
  const int i0 = blockIdx.x * 64;
  const int js = blockIdx.y;          // 0..11
  const int b  = blockIdx.z;
  const int jbase = js * 192;         // 3 j-tiles of 64 per chunk

  s8v ahi[8], alo[8];
  {
    const ushort_t* qh = Qh + ((size_t)b * S_TOT + i0 + w * 16 + li) * C_ + kg * 8;
    const ushort_t* ql = Ql + ((size_t)b * S_TOT + i0 + w * 16 + li) * C_ + kg * 8;
#pragma unroll
    for (int h = 0; h < 8; ++h) {
      ahi[h] = __builtin_bit_cast(s8v, *(const uint4*)(qh + h * 32));
      alo[h] = __builtin_bit_cast(s8v, *(const uint4*)(ql + h * 32));
    }
  }

  float zacc[4][8];
#pragma unroll
  for (int r = 0; r < 4; ++r)
#pragma unroll
    for (int h = 0; h < 8; ++h) zacc[r][h] = 0.f;

  for (int jt = 0; jt < 3; ++jt) {
    const int j0 = jbase + jt * 64;
    __syncthreads();
    for (int e = tid; e < 2048; e += 256) {
      int r = e >> 5, c = e & 31;
      size_t goff = ((size_t)b * S_TOT + j0 + r) * C_ + c * 8;
      int cs = c ^ (r & 7);
      kh_s[r * 32 + cs] = *(const uint4*)(Kh + goff);
      kl_s[r * 32 + cs] = *(const uint4*)(Kl + goff);
    }
    __syncthreads();

#pragma unroll
    for (int jsub = 0; jsub < 4; ++jsub) {
      const int rj = jsub * 16 + li;
      f32x4 sc[8];
#pragma unroll
      for (int h = 0; h < 8; ++h) {
        const int cs = (h * 4 + kg) ^ (rj & 7);
        s8v bhi = __builtin_bit_cast(s8v, kh_s[rj * 32 + cs]);
        s8v blo = __builtin_bit_cast(s8v, kl_s[rj * 32 + cs]);
        f32x4 acc = {0.f, 0.f, 0.f, 0.f};
        acc = __builtin_amdgcn_mfma_f32_16x16x32_bf16(ahi[h], bhi, acc, 0, 0, 0);
        acc = __builtin_amdgcn_mfma_f32_16x16x32_bf16(ahi[h], blo, acc, 0, 0, 0);
        acc = __builtin_amdgcn_mfma_f32_16x16x32_bf16(alo[h], bhi, acc, 0, 0, 0);
        sc[h] = acc;
      }
      const int jcol = j0 + jsub * 16 + li;
#pragma unroll
      for (int reg = 0; reg < 4; ++reg) {
        float s8_[8];
        float thr = -1e30f;
#pragma unroll
        for (int h = 0; h < 8; ++h) {
          s8_[h] = sc[h][reg] * INV_SQRT_DH;
          thr = fmaxf(thr, s8_[h]);
        }
        const int i = i0 + w * 16 + kg * 4 + reg;
#pragma unroll
        for (int h = 0; h < 8; ++h) {
          float mv = s8_[h] < thr ? -1e18f : s8_[h];
          float uf = __expf(mv);            // 0 exactly when masked
          ushort_t ub = bf16_rn(uf);
          U[((size_t)((b * 8 + h) * S_TOT + i)) * S_TOT + jcol] = ub;
          zacc[reg][h] += __uint_as_float((unsigned)ub << 16);
        }
      }
    }
  }

#pragma unroll
  for (int reg = 0; reg < 4; ++reg) {
#pragma unroll
    for (int h = 0; h < 8; ++h) {
      float z = zacc[reg][h];
      z += __shfl_xor(z, 1);
      z += __shfl_xor(z, 2);
      z += __shfl_xor(z, 4);
      z += __shfl_xor(z, 8);
      if (li == 0) {
        const int i = i0 + w * 16 + kg * 4 + reg;
        size_t sidx = ((size_t)(js * B_ + b) * HEADS_ + h) * S_TOT + i;
        st_z[sidx] = z;
      }
    }
  }
}

// ---------------------------------------------------------------------------
// Kernel 3: probs = U/Z + partial ctx via bf16 MFMA, j-split 3-way.
// grid (36 i-tiles, 8 h, 6 = jc*2+b) = 1728 blocks (6.75/CU), block 256.
// Each block covers 12 j-tiles; partial ctx (f32, iz applied, [b][s][c])
// -> Pv[jc]. Reg-prefetch pipeline, LDS 26.5 KB.
// ---------------------------------------------------------------------------
__global__ __launch_bounds__(256) void k_pv5(const ushort_t* __restrict__ U,
                                             const float* __restrict__ st_z,
                                             const ushort_t* __restrict__ VhT,
                                             const ushort_t* __restrict__ VlT,
                                             float* __restrict__ probs,
                                             float* __restrict__ part0,
                                             float* __restrict__ part1,
                                             float* __restrict__ part2) {
  __shared__ __align__(16) ushort_t u_s[2][64 * 64];
  __shared__ __align__(16) ushort_t vh_s[2][32 * 64];
  __shared__ __align__(16) ushort_t vl_s[2][32 * 64];
  __shared__ float row_iz[64];
  __shared__ int   row_sub[64];
  const int tid = threadIdx.x;
  const int w = tid >> 6, lane = tid & 63;
  const int li = lane & 15, kg = lane >> 4;
  const int i0 = blockIdx.x * 64;
  const int h  = blockIdx.y;
  const int z  = blockIdx.z;
  const int b  = z & 1;
  const int jc = z >> 1;              // 0..2
  float* part = (jc == 0) ? part0 : (jc == 1) ? part1 : part2;
  const int jlo = jc * 768;           // 12 tiles of 64

  if (tid < 64) {
    const int i = i0 + tid;
    float Z = 0.f;
#pragma unroll
    for (int js = 0; js < JSPLIT; ++js)
      Z += st_z[((size_t)(js * B_ + b) * HEADS_ + h) * S_TOT + i];
    if (Z == 0.f) { row_iz[tid] = 1.0f / (float)S_TOT; row_sub[tid] = 1; }
    else          { row_iz[tid] = 1.0f / Z;            row_sub[tid] = 0; }
  }

  const ushort_t* ub = U + ((size_t)((b * 8 + h) * S_TOT + i0)) * S_TOT;
  float* pb = probs + ((size_t)((b * 8 + h) * S_TOT + i0)) * S_TOT;
  const ushort_t* vhb = VhT + ((size_t)(b * C_ + h * 32)) * S_TOT;
  const ushort_t* vlb = VlT + ((size_t)(b * C_ + h * 32)) * S_TOT;

  const int r0_  = tid >> 3,         c8_0 = tid & 7;
  const int r1_  = (tid + 256) >> 3, c8_1 = tid & 7;
  const int dr_  = tid >> 3, c8v = tid & 7;
  const size_t uo0 = (size_t)r0_ * S_TOT + c8_0 * 8 + jlo;
  const size_t uo1 = (size_t)r1_ * S_TOT + c8_1 * 8 + jlo;
  const size_t vo  = (size_t)(dr_ & 31) * S_TOT + c8v * 8 + jlo;

  f32x4 acc[2];
  acc[0] = (f32x4){0.f, 0.f, 0.f, 0.f};
  acc[1] = (f32x4){0.f, 0.f, 0.f, 0.f};

  u16x8 ur0 = *(const u16x8*)(ub + uo0);
  u16x8 ur1 = *(const u16x8*)(ub + uo1);
  u16x8 vhr = *(const u16x8*)(vhb + vo);
  u16x8 vlr = *(const u16x8*)(vlb + vo);
  __syncthreads();

  for (int t = 0; t < 12; ++t) {
    const int j0 = jlo + t * 64;
    const int buf = t & 1;

    {
      u16x8 uu = ur0;
      if (row_sub[r0_]) uu = (u16x8){0x3F80,0x3F80,0x3F80,0x3F80,0x3F80,0x3F80,0x3F80,0x3F80};
      float iz = row_iz[r0_];
      float4 p0, p1;
      p0.x = __uint_as_float((unsigned)uu[0] << 16) * iz;
      p0.y = __uint_as_float((unsigned)uu[1] << 16) * iz;
      p0.z = __uint_as_float((unsigned)uu[2] << 16) * iz;
      p0.w = __uint_as_float((unsigned)uu[3] << 16) * iz;
      p1.x = __uint_as_float((unsigned)uu[4] << 16) * iz;
      p1.y = __uint_as_float((unsigned)uu[5] << 16) * iz;
      p1.z = __uint_as_float((unsigned)uu[6] << 16) * iz;
      p1.w = __uint_as_float((unsigned)uu[7] << 16) * iz;
      float* gp = pb + (size_t)r0_ * S_TOT + j0 + c8_0 * 8;
      *(float4*)gp = p0;
      *(float4*)(gp + 4) = p1;
      *(u16x8*)&u_s[buf][r0_ * 64 + (c8_0 ^ (r0_ & 7)) * 8] = uu;
    }
    {
      u16x8 uu = ur1;
      if (row_sub[r1_]) uu = (u16x8){0x3F80,0x3F80,0x3F80,0x3F80,0x3F80,0x3F80,0x3F80,0x3F80};
      float iz = row_iz[r1_];
      float4 p0, p1;
      p0.x = __uint_as_float((unsigned)uu[0] << 16) * iz;
      p0.y = __uint_as_float((unsigned)uu[1] << 16) * iz;
      p0.z = __uint_as_float((unsigned)uu[2] << 16) * iz;
      p0.w = __uint_as_float((unsigned)uu[3] << 16) * iz;
      p1.x = __uint_as_float((unsigned)uu[4] << 16) * iz;
      p1.y = __uint_as_float((unsigned)uu[5] << 16) * iz;
      p1.z = __uint_as_float((unsigned)uu[6] << 16) * iz;
      p1.w = __uint_as_float((unsigned)uu[7] << 16) * iz;
      float* gp = pb + (size_t)r1_ * S_TOT + j0 + c8_1 * 8;
      *(float4*)gp = p0;
      *(float4*)(gp + 4) = p1;
      *(u16x8*)&u_s[buf][r1_ * 64 + (c8_1 ^ (r1_ & 7)) * 8] = uu;
    }
    *(u16x8*)&vh_s[buf][(dr_ & 31) * 64 + (c8v ^ (dr_ & 7)) * 8] = vhr;
    *(u16x8*)&vl_s[buf][(dr_ & 31) * 64 + (c8v ^ (dr_ & 7)) * 8] = vlr;

    if (t < 11) {
      const size_t j1 = (size_t)(t + 1) * 64;
      ur0 = *(const u16x8*)(ub + uo0 + j1);
      ur1 = *(const u16x8*)(ub + uo1 + j1);
      vhr = *(const u16x8*)(vhb + vo + j1);
      vlr = *(const u16x8*)(vlb + vo + j1);
    }
    __syncthreads();

    {
      const int row = w * 16 + li;
      const int rs = li & 7;
      s8v a0 = __builtin_bit_cast(s8v, *(const uint4*)&u_s[buf][row * 64 + ((kg)     ^ rs) * 8]);
      s8v a1 = __builtin_bit_cast(s8v, *(const uint4*)&u_s[buf][row * 64 + ((4 + kg) ^ rs) * 8]);
#pragma unroll
      for (int dh = 0; dh < 2; ++dh) {
        const int d = dh * 16 + li;
        const int ds_ = li & 7;
        s8v bh0 = __builtin_bit_cast(s8v, *(const uint4*)&vh_s[buf][d * 64 + ((kg)     ^ ds_) * 8]);
        s8v bl0 = __builtin_bit_cast(s8v, *(const uint4*)&vl_s[buf][d * 64 + ((kg)     ^ ds_) * 8]);
        s8v bh1 = __builtin_bit_cast(s8v, *(const uint4*)&vh_s[buf][d * 64 + ((4 + kg) ^ ds_) * 8]);
        s8v bl1 = __builtin_bit_cast(s8v, *(const uint4*)&vl_s[buf][d * 64 + ((4 + kg) ^ ds_) * 8]);
        acc[dh] = __builtin_amdgcn_mfma_f32_16x16x32_bf16(a0, bh0, acc[dh], 0, 0, 0);
        acc[dh] = __builtin_amdgcn_mfma_f32_16x16x32_bf16(a0, bl0, acc[dh], 0, 0, 0);
        acc[dh] = __builtin_amdgcn_mfma_f32_16x16x32_bf16(a1, bh1, acc[dh], 0, 0, 0);
        acc[dh] = __builtin_amdgcn_mfma_f32_16x16x32_bf16(a1, bl1, acc[dh], 0, 0, 0);
      }
    }
  }

  // epilogue: partial ctx (f32, iz applied) in [b][s][c] layout
#pragma unroll
  for (int dh = 0; dh < 2; ++dh) {
#pragma unroll
    for (int reg = 0; reg < 4; ++reg) {
      const int irow = w * 16 + kg * 4 + reg;
      float v = acc[dh][reg] * row_iz[irow];
      part[((size_t)b * S_TOT + i0 + irow) * C_ + h * 32 + dh * 16 + li] = v;
    }
  }
}

// ---------------------------------------------------------------------------
// Kernel 3b: ctxT hi/lo = split(part0 + part1 + part2) (elementwise)
// ---------------------------------------------------------------------------
__global__ __launch_bounds__(256) void k_pvred(const float* __restrict__ p0,
                                               const float* __restrict__ p1,
                                               const float* __restrict__ p2,
                                               ushort_t* __restrict__ cTh,
                                               ushort_t* __restrict__ cTl) {
  size_t i4 = ((size_t)blockIdx.x * 256 + threadIdx.x) * 4;
  float4 a = *(const float4*)(p0 + i4);
  float4 b = *(const float4*)(p1 + i4);
  float4 c = *(const float4*)(p2 + i4);
  float v[4] = {a.x + b.x + c.x, a.y + b.y + c.y, a.z + b.z + c.z, a.w + b.w + c.w};
  ushort4 hv, lv;
  ushort_t* hp = (ushort_t*)&hv;
  ushort_t* lp = (ushort_t*)&lv;
#pragma unroll
  for (int q = 0; q < 4; ++q) {
    ushort_t h = bf16_rn(v[q]);
    float hf = __uint_as_float((unsigned)h << 16);
    hp[q] = h;
    lp[q] = bf16_rn(v[q] - hf);
  }
  *(ushort4*)(cTh + i4) = hv;
  *(ushort4*)(cTl + i4) = lv;
}

// ---------------------------------------------------------------------------
// Kernel 4a: repack+split conv weights -> Wh/Wl[tap][co][ci] (both convs, z)
// ---------------------------------------------------------------------------
__global__ __launch_bounds__(256) void k_repackW_split(
    const float* __restrict__ W1, const float* __restrict__ W2,
    ushort_t* __restrict__ Wh1, ushort_t* __restrict__ Wl1,
    ushort_t* __restrict__ Wh2, ushort_t* __restrict__ Wl2) {
  const int co = blockIdx.x, tap = blockIdx.y, zc = blockIdx.z, ci = threadIdx.x;
  const float* W = zc ? W2 : W1;
  ushort_t* Wh = zc ? Wh2 : Wh1;
  ushort_t* Wl = zc ? Wl2 : Wl1;
  float v = W[((size_t)co * 256 + ci) * 9 + tap];
  ushort_t h = bf16_rn(v);
  float r = __uint_as_float((unsigned)h << 16);
  ushort_t l = bf16_rn(v - r);
  size_t o = ((size_t)tap * 256 + co) * 256 + ci;
  Wh[o] = h;
  Wl[o] = l;
}

// ---------------------------------------------------------------------------
// Kernel 4b: conv MFMA v2 — input pre-split/transposed bf16 [b][s][c].
// grid (8 co-tiles, 24 y-pairs, 4 = b*2+ch), block 256; ch = ci half.
// ---------------------------------------------------------------------------
__global__ __launch_bounds__(256) void k_conv_mfma2(
    const ushort_t* __restrict__ inTh, const ushort_t* __restrict__ inTl,
    const ushort_t* __restrict__ Wh, const ushort_t* __restrict__ Wl,
    float* __restrict__ part0, float* __restrict__ part1) {
  __shared__ __align__(16) ushort_t in_sh[4 * 50 * 40];
  __shared__ __align__(16) ushort_t in_sl[4 * 50 * 40];
  const int tid = threadIdx.x;
  const int w = tid >> 6, lane = tid & 63;
  const int li = lane & 15, kg = lane >> 4;
  const int cg = w & 1, rw = w >> 1;
  const int co0 = blockIdx.x * 32;
  const int y0  = blockIdx.y * 2;
  const int z   = blockIdx.z;
  const int b = z >> 1, ch = z & 1;
  float* part = ch ? part1 : part0;

  for (int e = tid; e < 320; e += 256) {
    int sr = e / 80, rem = e % 80;
    int xl = (rem / 40) * 49, ci = rem % 40;
    in_sh[(sr * 50 + xl) * 40 + ci] = 0;
    in_sl[(sr * 50 + xl) * 40 + ci] = 0;
  }

  f32x4 acc[3];
#pragma unroll
  for (int xg = 0; xg < 3; ++xg) acc[xg] = (f32x4){0.f, 0.f, 0.f, 0.f};

  for (int c8 = 0; c8 < 4; ++c8) {
    const int ci0 = ch * 128 + c8 * 32;
    __syncthreads();
#pragma unroll
    for (int t = 0; t < 3; ++t) {
      int id = t * 256 + tid;
      int cig = id & 3;
      int xx  = (id >> 2) % 48;
      int sr  = id / 192;
      int gr  = y0 - 1 + sr;
      u16x8 vh = {0,0,0,0,0,0,0,0}, vl = {0,0,0,0,0,0,0,0};
      if (gr >= 0 && gr < 48) {
        size_t go = ((size_t)b * S_TOT + gr * 48 + xx) * C_ + ci0 + cig * 8;
        vh = *(const u16x8*)(inTh + go);
        vl = *(const u16x8*)(inTl + go);
      }
      int lo = (sr * 50 + xx + 1) * 40 + cig * 8;
      *(u16x8*)&in_sh[lo] = vh;
      *(u16x8*)&in_sl[lo] = vl;
    }
    __syncthreads();

#pragma unroll
    for (int ky = 0; ky < 3; ++ky) {
      const int srr = rw + ky;
#pragma unroll
      for (int kx = 0; kx < 3; ++kx) {
        const int tap = ky * 3 + kx;
        size_t wo = ((size_t)tap * 256 + co0 + cg * 16 + li) * 256 + ci0 + kg * 8;
        s8v ah = __builtin_bit_cast(s8v, *(const uint4*)(Wh + wo));
        s8v al = __builtin_bit_cast(s8v, *(const uint4*)(Wl + wo));
#pragma unroll
        for (int xg = 0; xg < 3; ++xg) {
          const int xl = xg * 16 + li + kx;
          s8v bh = __builtin_bit_cast(s8v, *(const uint4*)&in_sh[(srr * 50 + xl) * 40 + kg * 8]);
          s8v bl = __builtin_bit_cast(s8v, *(const uint4*)&in_sl[(srr * 50 + xl) * 40 + kg * 8]);
          acc[xg] = __builtin_amdgcn_mfma_f32_16x16x32_bf16(ah, bh, acc[xg], 0, 0, 0);
          acc[xg] = __builtin_amdgcn_mfma_f32_16x16x32_bf16(ah, bl, acc[xg], 0, 0, 0);
          acc[xg] = __builtin_amdgcn_mfma_f32_16x16x32_bf16(al, bh, acc[xg], 0, 0, 0);
        }
      }
    }
  }

  const int orow = y0 + rw;
#pragma unroll
  for (int reg = 0; reg < 4; ++reg) {
    const int co = co0 + cg * 16 + kg * 4 + reg;
    float* op = part + ((size_t)(b * 256 + co) * 48 + orow) * 48 + li;
#pragma unroll
    for (int xg = 0; xg < 3; ++xg) op[xg * 16] = acc[xg][reg];
  }
}

// ---------------------------------------------------------------------------
// Kernel 4c: y = selu(Cp0+Cp1+bias), transpose+split -> t1T hi/lo [b][s][c].
// grid (36 s-tiles, 4 co-tiles, B).
// ---------------------------------------------------------------------------
__global__ __launch_bounds__(256) void k_act_t(const float* __restrict__ p0,
                                               const float* __restrict__ p1,
                                               const float* __restrict__ bias,
                                               ushort_t* __restrict__ outTh,
                                               ushort_t* __restrict__ outTl) {
  __shared__ __align__(16) float t_s[64][65];
  const int tid = threadIdx.x;
  const int s0 = blockIdx.x * 64;
  const int co0 = blockIdx.y * 64;
  const int b  = blockIdx.z;

#pragma unroll
  for (int k = 0; k < 16; ++k) {
    int idx = tid + k * 256;
    int r = idx >> 6, c = idx & 63;
    size_t a = ((size_t)(b * 256 + co0 + r)) * S_TOT + s0 + c;
    float v = p0[a] + p1[a] + bias[co0 + r];
    v = 1.0507009873554805f * (v > 0.f ? v : 1.6732632423543772f * expm1f(v));
    t_s[r][c] = v;
  }
  __syncthreads();
#pragma unroll
  for (int k = 0; k < 16; ++k) {
    int idx = tid + k * 256;
    int p = idx >> 6, c = idx & 63;
    float v = t_s[c][p];
    ushort_t h = bf16_rn(v);
    float hf = __uint_as_float((unsigned)h << 16);
    ushort_t l = bf16_rn(v - hf);
    size_t o = ((size_t)b * S_TOT + s0 + p) * C_ + co0 + c;
    outTh[o] = h;
    outTl[o] = l;
  }
}

// ---------------------------------------------------------------------------
// Kernel 4d: out = Cp0 + Cp1 + bias (f32, no act)
// ---------------------------------------------------------------------------
__global__ __launch_bounds__(256) void k_act2(const float* __restrict__ p0,
                                              const float* __restrict__ p1,
                                              const float* __restrict__ bias,
                                              float* __restrict__ out) {
  size_t i4 = ((size_t)blockIdx.x * 256 + threadIdx.x) * 4;
  float4 a = *(const float4*)(p0 + i4);
  float4 b = *(const float4*)(p1 + i4);
  int co = (int)((i4 / (size_t)S_TOT) & 255);
  float bi = bias[co];
  float4 o;
  o.x = a.x + b.x + bi; o.y = a.y + b.y + bi;
  o.z = a.z + b.z + bi; o.w = a.w + b.w + bi;
  *(float4*)(out + i4) = o;
}

// ---------------------------------------------------------------------------
extern "C" void kernel_launch(void* const* d_in, const int* in_sizes, int n_in,
                              void* d_out, int out_size, void* d_ws, size_t ws_size,
                              hipStream_t stream) {
  const float* x   = (const float*)d_in[0];
  const float* ref = (const float*)d_in[1];
  const float* qW1 = (const float*)d_in[2];
  const float* qb1 = (const float*)d_in[3];
  const float* qW2 = (const float*)d_in[4];
  const float* qb2 = (const float*)d_in[5];
  const float* kW1 = (const float*)d_in[6];
  const float* kb1 = (const float*)d_in[7];
  const float* kW2 = (const float*)d_in[8];
  const float* kb2 = (const float*)d_in[9];
  const float* vW1 = (const float*)d_in[10];
  const float* vb1 = (const float*)d_in[11];
  const float* vW2 = (const float*)d_in[12];
  const float* vb2 = (const float*)d_in[13];
  const float* c1W = (const float*)d_in[14];
  const float* c1b = (const float*)d_in[15];
  const float* c2W = (const float*)d_in[16];
  const float* c2b = (const float*)d_in[17];

  float* out = (float*)d_out;
  float* probs = out + (size_t)B_ * C_ * S_TOT;       // [B][H][S][S]
  float* ws = (float*)d_ws;
  const size_t BSC = (size_t)B_ * S_TOT * C_;         // 1,179,648
  const size_t STATS = (size_t)JSPLIT * B_ * HEADS_ * S_TOT;
  const size_t WTSZ = (size_t)256 * 9 * 256;

  float* stz = ws;
  float* Pv0 = stz + STATS;
  float* Pv1 = Pv0 + BSC;
  float* Pv2 = Pv1 + BSC;
  float* endf = Pv2 + BSC;

  ushort_t* Qh  = (ushort_t*)endf;
  ushort_t* Ql  = Qh + BSC;
  ushort_t* Kh  = Ql + BSC;
  ushort_t* Kl  = Kh + BSC;
  ushort_t* VhT = Kl + BSC;
  ushort_t* VlT = VhT + BSC;
  ushort_t* cTh = VlT + BSC;
  ushort_t* cTl = cTh + BSC;
  ushort_t* t1h = cTl + BSC;
  ushort_t* t1l = t1h + BSC;
  ushort_t* Wh1 = t1l + BSC;
  ushort_t* Wl1 = Wh1 + WTSZ;
  ushort_t* Wh2 = Wl1 + WTSZ;
  ushort_t* Wl2 = Wh2 + WTSZ;
  ushort_t* Ubuf = Wl2 + WTSZ;   // ~170 MB

  // conv partials reuse Pv0/Pv1 (dead after pvred)
  float* Cp0 = Pv0;
  float* Cp1 = Pv1;

  dim3 blk(256);
  k_repackW_split<<<dim3(256, 9, 2), blk, 0, stream>>>(c1W, c2W, Wh1, Wl1, Wh2, Wl2);

  k_mlpf<<<dim3(72, B_, 3), blk, 0, stream>>>(x, ref,
                                              qW1, qb1, qW2, qb2,
                                              kW1, kb1, kW2, kb2,
                                              vW1, vb1, vW2, vb2,
                                              Qh, Ql, Kh, Kl, VhT, VlT);

  k_scores_mfma<<<dim3(36, JSPLIT, B_), blk, 0, stream>>>(Qh, Ql, Kh, Kl, Ubuf, stz);

  k_pv5<<<dim3(36, 8, 6), blk, 0, stream>>>(Ubuf, stz, VhT, VlT, probs, Pv0, Pv1, Pv2);
  k_pvred<<<dim3((int)(BSC / 1024)), blk, 0, stream>>>(Pv0, Pv1, Pv2, cTh, cTl);

  dim3 gconv(8, 24, 2 * B_);
  k_conv_mfma2<<<gconv, blk, 0, stream>>>(cTh, cTl, Wh1, Wl1, Cp0, Cp1);
  k_act_t<<<dim3(36, 4, B_), blk, 0, stream>>>(Cp0, Cp1, c1b, t1h, t1l);
  k_conv_mfma2<<<gconv, blk, 0, stream>>>(t1h, t1l, Wh2, Wl2, Cp0, Cp1);
  k_act2<<<dim3((int)(BSC / 1024)), blk, 0, stream>>>(Cp0, Cp1, c2b, out);
}